// Round 12
// baseline (253.450 us; speedup 1.0000x reference)
//
#include <hip/hip_runtime.h>
#include <math.h>

// Graph constants for this problem size (N=100000, E=1600000).
#define VSH   9                  // nodes per bucket = 512
#define VPB   512
#define MAXB  256                // max buckets (N <= 131072)
#define CAP   12288              // per-bucket edge capacity
#define BINCH 8192               // edges per k_bin block

// GEMM tiling
#define GN    128                // nodes per block
#define GSTR  132                // hT row stride in floats

// ---------------- bf16 helpers (RNE) ----------------
__device__ __forceinline__ float bflo(unsigned u) { return __uint_as_float(u << 16); }
__device__ __forceinline__ float bfhi(unsigned u) { return __uint_as_float(u & 0xFFFF0000u); }
__device__ __forceinline__ unsigned packbf2(float a, float b) {
    unsigned ua = __float_as_uint(a);
    unsigned ub = __float_as_uint(b);
    ua += 0x7FFFu + ((ua >> 16) & 1u);
    ub += 0x7FFFu + ((ub >> 16) & 1u);
    return (ua >> 16) | (ub & 0xFFFF0000u);
}

// ---------------- graph prep ----------------

// zero counters + per-slice sentinel rows (node id == n) of A and xw sentinel
__global__ void k_zero(int* __restrict__ bktCur, int* __restrict__ gtotal,
                       unsigned short* __restrict__ A, float* __restrict__ xwz,
                       int n, int stride) {
    int i = threadIdx.x;
    if (i < MAXB) bktCur[i] = 0;
    if (i == 0) *gtotal = 0;
    if (i < 64) {                      // slice s, channel j
        int s = i >> 3, j = i & 7;
        A[((size_t)s * stride + n) * 8 + j] = 0;
    }
    if (i < 3) xwz[i] = 0.f;
}

// Bin edges by dst bucket. Per block: LDS histogram -> per-bucket global
// reservation -> LDS stage ordered by bucket -> coalesced write-out.
__global__ void k_bin(const int* __restrict__ src, const int* __restrict__ dst,
                      int* __restrict__ bktCur, int* __restrict__ binned,
                      int e, int nb) {
    __shared__ int hist[MAXB];
    __shared__ int offs[MAXB];
    __shared__ int gbase[MAXB];
    __shared__ int lcur[MAXB];
    __shared__ int stage[BINCH];
    __shared__ unsigned char binid[BINCH];
    const int tid = threadIdx.x;
    const int blockStart = blockIdx.x * BINCH;
    const int chunk = min(BINCH, e - blockStart);

    for (int b = tid; b < MAXB; b += blockDim.x) hist[b] = 0;
    __syncthreads();

    for (int k = 0; k < BINCH / 1024; ++k) {
        int i0 = blockStart + k * 1024 + tid * 4;
        if (i0 + 3 < e) {
            int4 d4 = *(const int4*)(dst + i0);
            atomicAdd(&hist[d4.x >> VSH], 1);
            atomicAdd(&hist[d4.y >> VSH], 1);
            atomicAdd(&hist[d4.z >> VSH], 1);
            atomicAdd(&hist[d4.w >> VSH], 1);
        } else {
            for (int i = i0; i < e && i < i0 + 4; ++i)
                atomicAdd(&hist[dst[i] >> VSH], 1);
        }
    }
    __syncthreads();

    if (tid == 0) {
        int run = 0;
        for (int b = 0; b < nb; ++b) { offs[b] = run; run += hist[b]; }
    }
    __syncthreads();
    if (tid < nb) {
        gbase[tid] = (hist[tid] > 0) ? atomicAdd(&bktCur[tid], hist[tid]) : 0;
        lcur[tid] = offs[tid];
    }
    __syncthreads();

    for (int k = 0; k < BINCH / 1024; ++k) {
        int i0 = blockStart + k * 1024 + tid * 4;
        if (i0 + 3 < e) {
            int4 s4 = *(const int4*)(src + i0);
            int4 d4 = *(const int4*)(dst + i0);
            int bs[4] = { d4.x >> VSH, d4.y >> VSH, d4.z >> VSH, d4.w >> VSH };
            int pk[4] = { ((d4.x & (VPB - 1)) << 17) | s4.x,
                          ((d4.y & (VPB - 1)) << 17) | s4.y,
                          ((d4.z & (VPB - 1)) << 17) | s4.z,
                          ((d4.w & (VPB - 1)) << 17) | s4.w };
#pragma unroll
            for (int q = 0; q < 4; ++q) {
                int slot = atomicAdd(&lcur[bs[q]], 1);
                stage[slot] = pk[q];
                binid[slot] = (unsigned char)bs[q];
            }
        } else {
            for (int i = i0; i < e && i < i0 + 4; ++i) {
                int d = dst[i], b = d >> VSH;
                int slot = atomicAdd(&lcur[b], 1);
                stage[slot] = ((d & (VPB - 1)) << 17) | src[i];
                binid[slot] = (unsigned char)b;
            }
        }
    }
    __syncthreads();

    for (int j = tid; j < chunk; j += blockDim.x) {
        int b = binid[j];
        int idx = gbase[b] + (j - offs[b]);
        if (idx < CAP) binned[b * CAP + idx] = stage[j];
    }
}

// One block per bucket: LDS histogram, PADDED LDS scan (segments to x8,
// filler = sentinel node n), LDS scatter, coalesced col write-out.
// Also emits xw[nid] = x[nid]*dinv[nid].
__global__ void k_bucket(const int* __restrict__ binned, const int* __restrict__ bktCur,
                         int* __restrict__ gtotal, int* __restrict__ rowstart,
                         int* __restrict__ cntG, float* __restrict__ dinv,
                         int* __restrict__ col, const float* __restrict__ x,
                         float* __restrict__ xw, int n) {
    __shared__ int buf[VPB];
    __shared__ int cur[VPB];
    __shared__ int colStage[CAP];
    __shared__ int sBase;
    const int tid = threadIdx.x;
    const int b = blockIdx.x;
    const int nodeBase = b << VSH;
    const int count = min(bktCur[b], CAP);
    const int* bb = binned + b * CAP;

    buf[tid] = 0;
    __syncthreads();
    for (int i = tid; i < count; i += VPB)
        atomicAdd(&buf[bb[i] >> 17], 1);
    __syncthreads();
    int v = buf[tid];
    int vpad = (v + 7) & ~7;
    buf[tid] = vpad;
    __syncthreads();
    for (int off = 1; off < VPB; off <<= 1) {
        int t = (tid >= off) ? buf[tid - off] : 0;
        __syncthreads();
        buf[tid] += t;
        __syncthreads();
    }
    int excl = buf[tid] - vpad;
    if (tid == 0) sBase = atomicAdd(gtotal, buf[VPB - 1]);
    __syncthreads();
    int totalPad = buf[VPB - 1];
    int base = sBase;
    int nid = nodeBase + tid;
    if (nid < n) {
        float dv = rsqrtf((float)v + 1.0f);
        rowstart[nid] = base + excl;
        cntG[nid] = v;
        dinv[nid] = dv;
        const float* xr = x + (size_t)nid * 3;
        float* xo = xw + (size_t)nid * 3;
        xo[0] = xr[0] * dv;
        xo[1] = xr[1] * dv;
        xo[2] = xr[2] * dv;
    }
    cur[tid] = excl;
    for (int j = tid; j < totalPad && j < CAP; j += VPB) colStage[j] = n;
    __syncthreads();
    for (int i = tid; i < count; i += VPB) {
        int p = bb[i];
        int slot = atomicAdd(&cur[p >> 17], 1);
        colStage[slot] = p & 0x1FFFF;
    }
    __syncthreads();
    for (int j = tid; j < totalPad && j < CAP; j += VPB)
        col[base + j] = colStage[j];
}

// ---------------- layers ----------------

// Layer-0 (3-dim, pre-weighted payload): 4-lane groups, padded chunks.
__global__ void k_agg3(const float* __restrict__ xw, const float* __restrict__ dinv,
                       const int* __restrict__ rowstart, const int* __restrict__ cnt,
                       const int* __restrict__ col, float* __restrict__ xa, int n) {
    const int gl  = threadIdx.x & 3;
    const int grp = threadIdx.x >> 2;
    const int gpb = blockDim.x >> 2;
    for (int node = blockIdx.x * gpb + grp; node < n; node += gpb * gridDim.x) {
        float dn = dinv[node];
        float a = (gl < 3) ? xw[(size_t)node * 3 + gl] : 0.f;
        int s0 = rowstart[node];
        int cpad = (cnt[node] + 7) & ~7;
        for (int base = 0; base < cpad; base += 4) {
            int myidx = col[s0 + base + gl];
#pragma unroll
            for (int j = 0; j < 4; ++j) {
                int s = __shfl(myidx, j, 4);
                if (gl < 3) a += xw[(size_t)s * 3 + gl];
            }
        }
        if (gl < 3) xa[(size_t)node * 3 + gl] = a * dn;
    }
}

// Fused layer-1 GEMM: t1s = ( relu(xa@W0 + b0) @ W1 ) * dinv, bf16 SLICE-MAJOR out.
__global__ __launch_bounds__(128) void k_l1(const float* __restrict__ xa,
        const float* __restrict__ W0, const float* __restrict__ b0,
        const float* __restrict__ W1, const float* __restrict__ dinv,
        unsigned short* __restrict__ t, int n, int stride) {
    __shared__ float hT[64 * GSTR];
    __shared__ float Ws[64 * 64];
    __shared__ float W0s[3 * 64];
    __shared__ float b0s[64];
    __shared__ float xas[GN * 3];
    const int tid = threadIdx.x;
    const int n0 = blockIdx.x * GN;

    {
        const float4* W4 = (const float4*)W1;
        float4* Ws4 = (float4*)Ws;
        for (int i = tid; i < 1024; i += 128) Ws4[i] = W4[i];
    }
    if (tid < 64) b0s[tid] = b0[tid];
    for (int i = tid; i < 192; i += 128) W0s[i] = W0[i];
    for (int i = tid; i < GN * 3; i += 128) {
        int gi = n0 * 3 + i;
        xas[i] = (gi < n * 3) ? xa[gi] : 0.f;
    }
    __syncthreads();

    for (int p = 0; p < 16; ++p) {
        int idx = p * 128 + tid;
        int r = idx >> 4;
        int c4 = idx & 15;
        float x0 = xas[r * 3 + 0], x1 = xas[r * 3 + 1], x2 = xas[r * 3 + 2];
#pragma unroll
        for (int q = 0; q < 4; ++q) {
            int c = c4 * 4 + q;
            float h = fmaf(x0, W0s[c], fmaf(x1, W0s[64 + c], fmaf(x2, W0s[128 + c], b0s[c])));
            hT[c * GSTR + r] = fmaxf(h, 0.f);
        }
    }
    __syncthreads();

    const int lane = tid & 63;
    const int wave = tid >> 6;
    const int ng = lane >> 3;
    const int cg = lane & 7;
    const int nodeLoc = wave * 64 + ng * 8;

    float4 acc[8][2];
#pragma unroll
    for (int i = 0; i < 8; ++i) {
        acc[i][0] = make_float4(0.f, 0.f, 0.f, 0.f);
        acc[i][1] = make_float4(0.f, 0.f, 0.f, 0.f);
    }

#pragma unroll 4
    for (int k = 0; k < 64; ++k) {
        const float4* ap = (const float4*)(hT + k * GSTR + nodeLoc);
        const float4* bp = (const float4*)(Ws + k * 64 + cg * 8);
        float4 a0 = ap[0], a1 = ap[1];
        float4 b0v = bp[0], b1v = bp[1];
        const float av[8] = { a0.x, a0.y, a0.z, a0.w, a1.x, a1.y, a1.z, a1.w };
#pragma unroll
        for (int i = 0; i < 8; ++i) {
            acc[i][0].x = fmaf(av[i], b0v.x, acc[i][0].x);
            acc[i][0].y = fmaf(av[i], b0v.y, acc[i][0].y);
            acc[i][0].z = fmaf(av[i], b0v.z, acc[i][0].z);
            acc[i][0].w = fmaf(av[i], b0v.w, acc[i][0].w);
            acc[i][1].x = fmaf(av[i], b1v.x, acc[i][1].x);
            acc[i][1].y = fmaf(av[i], b1v.y, acc[i][1].y);
            acc[i][1].z = fmaf(av[i], b1v.z, acc[i][1].z);
            acc[i][1].w = fmaf(av[i], b1v.w, acc[i][1].w);
        }
    }

#pragma unroll
    for (int i = 0; i < 8; ++i) {
        int row = n0 + nodeLoc + i;
        if (row < n) {
            float dv = dinv[row];
            uint4 pk;
            pk.x = packbf2(acc[i][0].x * dv, acc[i][0].y * dv);
            pk.y = packbf2(acc[i][0].z * dv, acc[i][0].w * dv);
            pk.z = packbf2(acc[i][1].x * dv, acc[i][1].y * dv);
            pk.w = packbf2(acc[i][1].z * dv, acc[i][1].w * dv);
            *(uint4*)(t + ((size_t)cg * stride + row) * 8) = pk;   // slice cg
        }
    }
}

// Layer-2 GEMM: t2s = (h2 @ W2) * dinv; h2 input bf16 SLICE-MAJOR, out slice-major.
__global__ __launch_bounds__(128) void k_gemm64(const unsigned short* __restrict__ h,
        const float* __restrict__ W, const float* __restrict__ dinv,
        unsigned short* __restrict__ t, int n, int stride) {
    __shared__ float hT[64 * GSTR];
    __shared__ float Ws[64 * 64];
    const int tid = threadIdx.x;
    const int n0 = blockIdx.x * GN;

    {
        const float4* W4 = (const float4*)W;
        float4* Ws4 = (float4*)Ws;
        for (int i = tid; i < 1024; i += 128) Ws4[i] = W4[i];
    }
    // stage: slice p, node n0+tid — coalesced 16B reads per slice stream
    for (int p = 0; p < 8; ++p) {
        int r = tid;                     // local node 0..127
        int gr = n0 + r;
        uint4 v = (gr < n) ? *(const uint4*)(h + ((size_t)p * stride + gr) * 8)
                           : make_uint4(0u, 0u, 0u, 0u);
        int c = p * 8;
        hT[(c + 0) * GSTR + r] = bflo(v.x);
        hT[(c + 1) * GSTR + r] = bfhi(v.x);
        hT[(c + 2) * GSTR + r] = bflo(v.y);
        hT[(c + 3) * GSTR + r] = bfhi(v.y);
        hT[(c + 4) * GSTR + r] = bflo(v.z);
        hT[(c + 5) * GSTR + r] = bfhi(v.z);
        hT[(c + 6) * GSTR + r] = bflo(v.w);
        hT[(c + 7) * GSTR + r] = bfhi(v.w);
    }
    __syncthreads();

    const int lane = tid & 63;
    const int wave = tid >> 6;
    const int ng = lane >> 3;
    const int cg = lane & 7;
    const int nodeLoc = wave * 64 + ng * 8;

    float4 acc[8][2];
#pragma unroll
    for (int i = 0; i < 8; ++i) {
        acc[i][0] = make_float4(0.f, 0.f, 0.f, 0.f);
        acc[i][1] = make_float4(0.f, 0.f, 0.f, 0.f);
    }

#pragma unroll 4
    for (int k = 0; k < 64; ++k) {
        const float4* ap = (const float4*)(hT + k * GSTR + nodeLoc);
        const float4* bp = (const float4*)(Ws + k * 64 + cg * 8);
        float4 a0 = ap[0], a1 = ap[1];
        float4 b0 = bp[0], b1 = bp[1];
        const float av[8] = { a0.x, a0.y, a0.z, a0.w, a1.x, a1.y, a1.z, a1.w };
#pragma unroll
        for (int i = 0; i < 8; ++i) {
            acc[i][0].x = fmaf(av[i], b0.x, acc[i][0].x);
            acc[i][0].y = fmaf(av[i], b0.y, acc[i][0].y);
            acc[i][0].z = fmaf(av[i], b0.z, acc[i][0].z);
            acc[i][0].w = fmaf(av[i], b0.w, acc[i][0].w);
            acc[i][1].x = fmaf(av[i], b1.x, acc[i][1].x);
            acc[i][1].y = fmaf(av[i], b1.y, acc[i][1].y);
            acc[i][1].z = fmaf(av[i], b1.z, acc[i][1].z);
            acc[i][1].w = fmaf(av[i], b1.w, acc[i][1].w);
        }
    }

#pragma unroll
    for (int i = 0; i < 8; ++i) {
        int row = n0 + nodeLoc + i;
        if (row < n) {
            float dv = dinv[row];
            uint4 pk;
            pk.x = packbf2(acc[i][0].x * dv, acc[i][0].y * dv);
            pk.y = packbf2(acc[i][0].z * dv, acc[i][0].w * dv);
            pk.z = packbf2(acc[i][1].x * dv, acc[i][1].y * dv);
            pk.w = packbf2(acc[i][1].z * dv, acc[i][1].w * dv);
            *(uint4*)(t + ((size_t)cg * stride + row) * 8) = pk;
        }
    }
}

// Slice-mode aggregation (layer-1): slice = blockIdx&7 -> XCD-affine; each XCD's
// gathers hit its own 1.6MB L2-resident slice. 8-lane group = 8 EDGES in
// parallel (each lane gathers its own edge's 16B chunk); butterfly reduce.
// h2[slice][node] = relu(b1[slice*8+j] + dn*(t1s[node] + sum_s t1s[s]))
__global__ void k_aggs(const unsigned short* __restrict__ t, const float* __restrict__ dinv,
                       const int* __restrict__ rowstart, const int* __restrict__ cnt,
                       const int* __restrict__ col, const float* __restrict__ b,
                       unsigned short* __restrict__ out, int n, int stride) {
    const int gl    = threadIdx.x & 7;
    const int grp   = threadIdx.x >> 3;      // 0..31
    const int slice = blockIdx.x & 7;
    const int bs    = blockIdx.x >> 3;
    const int gpb   = blockDim.x >> 3;       // 32
    const int gps   = (gridDim.x >> 3) * gpb; // groups per slice
    const unsigned short* ts = t + (size_t)slice * stride * 8;
    unsigned short* os = out + (size_t)slice * stride * 8;
    float b0v = b[slice * 8 + 0], b1v = b[slice * 8 + 1];
    float b2v = b[slice * 8 + 2], b3v = b[slice * 8 + 3];
    float b4v = b[slice * 8 + 4], b5v = b[slice * 8 + 5];
    float b6v = b[slice * 8 + 6], b7v = b[slice * 8 + 7];
    for (int node = bs * gpb + grp; node < n; node += gps) {
        int s0 = rowstart[node];
        int cpad = (cnt[node] + 7) & ~7;
        float a0 = 0.f, a1 = 0.f, a2 = 0.f, a3 = 0.f;
        float a4 = 0.f, a5 = 0.f, a6 = 0.f, a7 = 0.f;
        for (int base = 0; base < cpad; base += 8) {
            int s = col[s0 + base + gl];                      // own edge
            uint4 g = *(const uint4*)(ts + (size_t)s * 8);    // 16B slice chunk
            a0 += bflo(g.x); a1 += bfhi(g.x);
            a2 += bflo(g.y); a3 += bfhi(g.y);
            a4 += bflo(g.z); a5 += bfhi(g.z);
            a6 += bflo(g.w); a7 += bfhi(g.w);
        }
#pragma unroll
        for (int off = 4; off > 0; off >>= 1) {
            a0 += __shfl_xor(a0, off, 8); a1 += __shfl_xor(a1, off, 8);
            a2 += __shfl_xor(a2, off, 8); a3 += __shfl_xor(a3, off, 8);
            a4 += __shfl_xor(a4, off, 8); a5 += __shfl_xor(a5, off, 8);
            a6 += __shfl_xor(a6, off, 8); a7 += __shfl_xor(a7, off, 8);
        }
        if (gl == 0) {
            uint4 tv = *(const uint4*)(ts + (size_t)node * 8);
            float dn = dinv[node];
            a0 += bflo(tv.x); a1 += bfhi(tv.x);
            a2 += bflo(tv.y); a3 += bfhi(tv.y);
            a4 += bflo(tv.z); a5 += bfhi(tv.z);
            a6 += bflo(tv.w); a7 += bfhi(tv.w);
            uint4 o;
            o.x = packbf2(fmaxf(fmaf(a0, dn, b0v), 0.f), fmaxf(fmaf(a1, dn, b1v), 0.f));
            o.y = packbf2(fmaxf(fmaf(a2, dn, b2v), 0.f), fmaxf(fmaf(a3, dn, b3v), 0.f));
            o.z = packbf2(fmaxf(fmaf(a4, dn, b4v), 0.f), fmaxf(fmaf(a5, dn, b5v), 0.f));
            o.w = packbf2(fmaxf(fmaf(a6, dn, b6v), 0.f), fmaxf(fmaf(a7, dn, b7v), 0.f));
            *(uint4*)(os + (size_t)node * 8) = o;
        }
    }
}

// Slice-mode final aggregation + head partial:
// partial[slice][node] = sum_j relu(b2[..]+dn*agg_j) * Wo[slice*8+j]
__global__ void k_aggout(const unsigned short* __restrict__ t, const float* __restrict__ dinv,
                         const int* __restrict__ rowstart, const int* __restrict__ cnt,
                         const int* __restrict__ col, const float* __restrict__ b,
                         const float* __restrict__ Wo, float* __restrict__ partial,
                         int n, int stride) {
    const int gl    = threadIdx.x & 7;
    const int grp   = threadIdx.x >> 3;
    const int slice = blockIdx.x & 7;
    const int bs    = blockIdx.x >> 3;
    const int gpb   = blockDim.x >> 3;
    const int gps   = (gridDim.x >> 3) * gpb;
    const unsigned short* ts = t + (size_t)slice * stride * 8;
    float* ps = partial + (size_t)slice * n;
    float b0v = b[slice * 8 + 0], b1v = b[slice * 8 + 1];
    float b2v = b[slice * 8 + 2], b3v = b[slice * 8 + 3];
    float b4v = b[slice * 8 + 4], b5v = b[slice * 8 + 5];
    float b6v = b[slice * 8 + 6], b7v = b[slice * 8 + 7];
    float w0v = Wo[slice * 8 + 0], w1v = Wo[slice * 8 + 1];
    float w2v = Wo[slice * 8 + 2], w3v = Wo[slice * 8 + 3];
    float w4v = Wo[slice * 8 + 4], w5v = Wo[slice * 8 + 5];
    float w6v = Wo[slice * 8 + 6], w7v = Wo[slice * 8 + 7];
    for (int node = bs * gpb + grp; node < n; node += gps) {
        int s0 = rowstart[node];
        int cpad = (cnt[node] + 7) & ~7;
        float a0 = 0.f, a1 = 0.f, a2 = 0.f, a3 = 0.f;
        float a4 = 0.f, a5 = 0.f, a6 = 0.f, a7 = 0.f;
        for (int base = 0; base < cpad; base += 8) {
            int s = col[s0 + base + gl];
            uint4 g = *(const uint4*)(ts + (size_t)s * 8);
            a0 += bflo(g.x); a1 += bfhi(g.x);
            a2 += bflo(g.y); a3 += bfhi(g.y);
            a4 += bflo(g.z); a5 += bfhi(g.z);
            a6 += bflo(g.w); a7 += bfhi(g.w);
        }
#pragma unroll
        for (int off = 4; off > 0; off >>= 1) {
            a0 += __shfl_xor(a0, off, 8); a1 += __shfl_xor(a1, off, 8);
            a2 += __shfl_xor(a2, off, 8); a3 += __shfl_xor(a3, off, 8);
            a4 += __shfl_xor(a4, off, 8); a5 += __shfl_xor(a5, off, 8);
            a6 += __shfl_xor(a6, off, 8); a7 += __shfl_xor(a7, off, 8);
        }
        if (gl == 0) {
            uint4 tv = *(const uint4*)(ts + (size_t)node * 8);
            float dn = dinv[node];
            a0 += bflo(tv.x); a1 += bfhi(tv.x);
            a2 += bflo(tv.y); a3 += bfhi(tv.y);
            a4 += bflo(tv.z); a5 += bfhi(tv.z);
            a6 += bflo(tv.w); a7 += bfhi(tv.w);
            float v = fmaxf(fmaf(a0, dn, b0v), 0.f) * w0v
                    + fmaxf(fmaf(a1, dn, b1v), 0.f) * w1v
                    + fmaxf(fmaf(a2, dn, b2v), 0.f) * w2v
                    + fmaxf(fmaf(a3, dn, b3v), 0.f) * w3v
                    + fmaxf(fmaf(a4, dn, b4v), 0.f) * w4v
                    + fmaxf(fmaf(a5, dn, b5v), 0.f) * w5v
                    + fmaxf(fmaf(a6, dn, b6v), 0.f) * w6v
                    + fmaxf(fmaf(a7, dn, b7v), 0.f) * w7v;
            ps[node] = v;
        }
    }
}

// out[i] = sigmoid( sum_slices partial[s][i] + bo )   (fixed order: deterministic)
__global__ void k_head(const float* __restrict__ partial, const float* __restrict__ bo,
                       float* __restrict__ out, int n) {
    int i = blockIdx.x * blockDim.x + threadIdx.x;
    if (i < n) {
        float v = bo[0];
#pragma unroll
        for (int s = 0; s < 8; ++s) v += partial[(size_t)s * n + i];
        out[i] = 1.0f / (1.0f + expf(-v));
    }
}

// ---------------- launch ----------------

extern "C" void kernel_launch(void* const* d_in, const int* in_sizes, int n_in,
                              void* d_out, int out_size, void* d_ws, size_t ws_size,
                              hipStream_t stream) {
    const float* x  = (const float*)d_in[0];
    const int*   ei = (const int*)d_in[1];
    const float* W0 = (const float*)d_in[2];
    const float* b0 = (const float*)d_in[3];
    const float* W1 = (const float*)d_in[4];
    const float* b1 = (const float*)d_in[5];
    const float* W2 = (const float*)d_in[6];
    const float* b2 = (const float*)d_in[7];
    const float* Wo = (const float*)d_in[8];
    const float* bo = (const float*)d_in[9];
    float* out = (float*)d_out;

    const int N = in_sizes[0] / 3;
    const int E = in_sizes[1] / 2;
    const int* src = ei;
    const int* dst = ei + E;
    const int nb = (N + VPB - 1) >> VSH;
    const int stride = N + 1;                 // per-slice row count

    char* w = (char*)d_ws;
    size_t off = 0;
    auto take = [&](size_t bytes) -> void* {
        void* p = w + off;
        off = (off + bytes + 255) & ~(size_t)255;
        return p;
    };
    float* dinv     = (float*)take((size_t)N * 4);
    int*   cnt      = (int*)take((size_t)N * 4);
    int*   rowstart = (int*)take((size_t)N * 4);
    int*   gtotal   = (int*)take(4);
    int*   bktCur   = (int*)take(MAXB * 4);
    float* xw       = (float*)take((size_t)(N + 1) * 3 * 4);
    float* xa       = (float*)take((size_t)N * 3 * 4);
    int*   col      = (int*)take(((size_t)E + 8 * (size_t)N) * 4);
    unsigned short* A = (unsigned short*)take((size_t)8 * stride * 8 * 2); // slice-major
    unsigned short* B = (unsigned short*)take((size_t)8 * stride * 8 * 2); // slice-major
    float* partial  = (float*)take((size_t)8 * N * 4);
    int*   binned   = (int*)take((size_t)MAXB * CAP * 4);
    (void)ws_size; (void)n_in; (void)out_size;

    const int TB = 256;
    // graph prep
    k_zero  <<<1, 256, 0, stream>>>(bktCur, gtotal, A, xw + (size_t)N * 3, N, stride);
    k_bin   <<<(E + BINCH - 1) / BINCH, TB, 0, stream>>>(src, dst, bktCur, binned, E, nb);
    k_bucket<<<nb, VPB, 0, stream>>>(binned, bktCur, gtotal, rowstart, cnt, dinv, col, x, xw, N);

    // layer 0 agg (3-dim)
    k_agg3  <<<2048, TB, 0, stream>>>(xw, dinv, rowstart, cnt, col, xa, N);
    // layer 1: fused h0 + GEMM W1 -> slice-major bf16 A
    k_l1    <<<(N + GN - 1) / GN, 128, 0, stream>>>(xa, W0, b0, W1, dinv, A, N, stride);
    // layer-1 aggregation, XCD-affine slices: A -> B (h2, slice-major)
    k_aggs  <<<2048, TB, 0, stream>>>(A, dinv, rowstart, cnt, col, b1, B, N, stride);
    // layer 2 GEMM: B -> A (t2s, slice-major)
    k_gemm64<<<(N + GN - 1) / GN, 128, 0, stream>>>(B, W2, dinv, A, N, stride);
    // layer-2 aggregation + head partials, then reduce
    k_aggout<<<2048, TB, 0, stream>>>(A, dinv, rowstart, cnt, col, b2, Wo, partial, N, stride);
    k_head  <<<(N + TB - 1) / TB, TB, 0, stream>>>(partial, bo, out, N);
}

// Round 13
// 174.878 us; speedup vs baseline: 1.4493x; 1.4493x over previous
//
#include <hip/hip_runtime.h>
#include <math.h>

// Graph constants for this problem size (N=100000, E=1600000).
#define VSH   9                  // nodes per bucket = 512
#define VPB   512
#define MAXB  256                // max buckets (N <= 131072)
#define CAP   12288              // per-bucket edge capacity (padded)
#define BINCH 8192               // edges per k_bin block

// GEMM tiling
#define GN    128                // nodes per block
#define GSTR  132                // hT row stride in floats (16B-aligned; 2-way banks)

// ---------------- bf16 helpers (RNE) ----------------
__device__ __forceinline__ float bflo(unsigned u) { return __uint_as_float(u << 16); }
__device__ __forceinline__ float bfhi(unsigned u) { return __uint_as_float(u & 0xFFFF0000u); }
__device__ __forceinline__ unsigned packbf2(float a, float b) {
    unsigned ua = __float_as_uint(a);
    unsigned ub = __float_as_uint(b);
    ua += 0x7FFFu + ((ua >> 16) & 1u);   // round-to-nearest-even
    ub += 0x7FFFu + ((ub >> 16) & 1u);
    return (ua >> 16) | (ub & 0xFFFF0000u);
}

// ---------------- graph prep ----------------

// zero counters + the sentinel rows (node id == n) of t and xw
__global__ void k_zero(int* __restrict__ bktCur, int* __restrict__ gtotal,
                       unsigned short* __restrict__ tz, float* __restrict__ xwz) {
    int i = threadIdx.x;
    if (i < MAXB) bktCur[i] = 0;
    if (i == 0) *gtotal = 0;
    if (i < 64) tz[i] = 0;        // bf16 zero row
    if (i < 3) xwz[i] = 0.f;
}

// Bin edges by dst bucket. Per block: LDS histogram -> per-bucket global
// reservation -> LDS stage ordered by bucket -> coalesced write-out.
__global__ void k_bin(const int* __restrict__ src, const int* __restrict__ dst,
                      int* __restrict__ bktCur, int* __restrict__ binned,
                      int e, int nb) {
    __shared__ int hist[MAXB];
    __shared__ int offs[MAXB];
    __shared__ int gbase[MAXB];
    __shared__ int lcur[MAXB];
    __shared__ int stage[BINCH];
    __shared__ unsigned char binid[BINCH];
    const int tid = threadIdx.x;
    const int blockStart = blockIdx.x * BINCH;
    const int chunk = min(BINCH, e - blockStart);

    for (int b = tid; b < MAXB; b += blockDim.x) hist[b] = 0;
    __syncthreads();

    // pass 1: histogram
    for (int k = 0; k < BINCH / 1024; ++k) {
        int i0 = blockStart + k * 1024 + tid * 4;
        if (i0 + 3 < e) {
            int4 d4 = *(const int4*)(dst + i0);
            atomicAdd(&hist[d4.x >> VSH], 1);
            atomicAdd(&hist[d4.y >> VSH], 1);
            atomicAdd(&hist[d4.z >> VSH], 1);
            atomicAdd(&hist[d4.w >> VSH], 1);
        } else {
            for (int i = i0; i < e && i < i0 + 4; ++i)
                atomicAdd(&hist[dst[i] >> VSH], 1);
        }
    }
    __syncthreads();

    // exclusive scan of hist (serial by t0 — nb<=256, once per block)
    if (tid == 0) {
        int run = 0;
        for (int b = 0; b < nb; ++b) { offs[b] = run; run += hist[b]; }
    }
    __syncthreads();
    if (tid < nb) {
        gbase[tid] = (hist[tid] > 0) ? atomicAdd(&bktCur[tid], hist[tid]) : 0;
        lcur[tid] = offs[tid];
    }
    __syncthreads();

    // pass 2: stage ordered by bucket (re-read edges, L2-hot)
    for (int k = 0; k < BINCH / 1024; ++k) {
        int i0 = blockStart + k * 1024 + tid * 4;
        if (i0 + 3 < e) {
            int4 s4 = *(const int4*)(src + i0);
            int4 d4 = *(const int4*)(dst + i0);
            int bs[4] = { d4.x >> VSH, d4.y >> VSH, d4.z >> VSH, d4.w >> VSH };
            int pk[4] = { ((d4.x & (VPB - 1)) << 17) | s4.x,
                          ((d4.y & (VPB - 1)) << 17) | s4.y,
                          ((d4.z & (VPB - 1)) << 17) | s4.z,
                          ((d4.w & (VPB - 1)) << 17) | s4.w };
#pragma unroll
            for (int q = 0; q < 4; ++q) {
                int slot = atomicAdd(&lcur[bs[q]], 1);
                stage[slot] = pk[q];
                binid[slot] = (unsigned char)bs[q];
            }
        } else {
            for (int i = i0; i < e && i < i0 + 4; ++i) {
                int d = dst[i], b = d >> VSH;
                int slot = atomicAdd(&lcur[b], 1);
                stage[slot] = ((d & (VPB - 1)) << 17) | src[i];
                binid[slot] = (unsigned char)b;
            }
        }
    }
    __syncthreads();

    // pass 3: coalesced write-out per bucket run
    for (int j = tid; j < chunk; j += blockDim.x) {
        int b = binid[j];
        int idx = gbase[b] + (j - offs[b]);
        if (idx < CAP) binned[b * CAP + idx] = stage[j];
    }
}

// One block per bucket: LDS histogram (-> deg/cnt/dinv), PADDED LDS scan
// (segments rounded up to multiples of 8, filler = sentinel node n), one atomic
// for the bucket CSR base, LDS scatter, coalesced col write-out.
// Also emits xw[nid] = x[nid]*dinv[nid].
__global__ void k_bucket(const int* __restrict__ binned, const int* __restrict__ bktCur,
                         int* __restrict__ gtotal, int* __restrict__ rowstart,
                         int* __restrict__ cntG, float* __restrict__ dinv,
                         int* __restrict__ col, const float* __restrict__ x,
                         float* __restrict__ xw, int n) {
    __shared__ int buf[VPB];
    __shared__ int cur[VPB];
    __shared__ int colStage[CAP];
    __shared__ int sBase;
    const int tid = threadIdx.x;                 // blockDim = VPB
    const int b = blockIdx.x;
    const int nodeBase = b << VSH;
    const int count = min(bktCur[b], CAP);
    const int* bb = binned + b * CAP;

    buf[tid] = 0;
    __syncthreads();
    for (int i = tid; i < count; i += VPB)
        atomicAdd(&buf[bb[i] >> 17], 1);
    __syncthreads();
    int v = buf[tid];                            // real degree
    int vpad = (v + 7) & ~7;                     // padded segment length
    buf[tid] = vpad;
    __syncthreads();
    for (int off = 1; off < VPB; off <<= 1) {
        int t = (tid >= off) ? buf[tid - off] : 0;
        __syncthreads();
        buf[tid] += t;
        __syncthreads();
    }
    int excl = buf[tid] - vpad;
    if (tid == 0) sBase = atomicAdd(gtotal, buf[VPB - 1]);
    __syncthreads();
    int totalPad = buf[VPB - 1];
    int base = sBase;
    int nid = nodeBase + tid;
    if (nid < n) {
        float dv = rsqrtf((float)v + 1.0f);
        rowstart[nid] = base + excl;
        cntG[nid] = v;
        dinv[nid] = dv;
        const float* xr = x + (size_t)nid * 3;
        float* xo = xw + (size_t)nid * 3;
        xo[0] = xr[0] * dv;
        xo[1] = xr[1] * dv;
        xo[2] = xr[2] * dv;
    }
    cur[tid] = excl;
    for (int j = tid; j < totalPad && j < CAP; j += VPB) colStage[j] = n;
    __syncthreads();
    for (int i = tid; i < count; i += VPB) {
        int p = bb[i];
        int slot = atomicAdd(&cur[p >> 17], 1);
        colStage[slot] = p & 0x1FFFF;
    }
    __syncthreads();
    for (int j = tid; j < totalPad && j < CAP; j += VPB)
        col[base + j] = colStage[j];
}

// ---------------- layers ----------------

// Layer-0: aggregation commutes with the GEMM; payload xw = x*dinv pre-weighted.
// 4-lane group per node, lane = channel (0..2), branch-free padded chunks.
__global__ void k_agg3(const float* __restrict__ xw, const float* __restrict__ dinv,
                       const int* __restrict__ rowstart, const int* __restrict__ cnt,
                       const int* __restrict__ col, float* __restrict__ xa, int n) {
    const int gl  = threadIdx.x & 3;
    const int grp = threadIdx.x >> 2;
    const int gpb = blockDim.x >> 2;
    for (int node = blockIdx.x * gpb + grp; node < n; node += gpb * gridDim.x) {
        float dn = dinv[node];
        float a = (gl < 3) ? xw[(size_t)node * 3 + gl] : 0.f;
        int s0 = rowstart[node];
        int cpad = (cnt[node] + 7) & ~7;
        for (int base = 0; base < cpad; base += 4) {
            int myidx = col[s0 + base + gl];
#pragma unroll
            for (int j = 0; j < 4; ++j) {
                int s = __shfl(myidx, j, 4);
                if (gl < 3) a += xw[(size_t)s * 3 + gl];   // sentinel row is zeros
            }
        }
        if (gl < 3) xa[(size_t)node * 3 + gl] = a * dn;
    }
}

// Fused layer-1 GEMM: t1s = ( relu(xa@W0 + b0) @ W1 ) * dinv, bf16 out.
__global__ __launch_bounds__(128) void k_l1(const float* __restrict__ xa,
        const float* __restrict__ W0, const float* __restrict__ b0,
        const float* __restrict__ W1, const float* __restrict__ dinv,
        unsigned short* __restrict__ t, int n) {
    __shared__ float hT[64 * GSTR];      // [k][node], stride GSTR
    __shared__ float Ws[64 * 64];        // [k][j] = W1
    __shared__ float W0s[3 * 64];
    __shared__ float b0s[64];
    __shared__ float xas[GN * 3];
    const int tid = threadIdx.x;
    const int n0 = blockIdx.x * GN;

    {
        const float4* W4 = (const float4*)W1;
        float4* Ws4 = (float4*)Ws;
        for (int i = tid; i < 1024; i += 128) Ws4[i] = W4[i];
    }
    if (tid < 64) b0s[tid] = b0[tid];
    for (int i = tid; i < 192; i += 128) W0s[i] = W0[i];
    for (int i = tid; i < GN * 3; i += 128) {
        int gi = n0 * 3 + i;
        xas[i] = (gi < n * 3) ? xa[gi] : 0.f;
    }
    __syncthreads();

    for (int p = 0; p < 16; ++p) {
        int idx = p * 128 + tid;
        int r = idx >> 4;
        int c4 = idx & 15;
        float x0 = xas[r * 3 + 0], x1 = xas[r * 3 + 1], x2 = xas[r * 3 + 2];
#pragma unroll
        for (int q = 0; q < 4; ++q) {
            int c = c4 * 4 + q;
            float h = fmaf(x0, W0s[c], fmaf(x1, W0s[64 + c], fmaf(x2, W0s[128 + c], b0s[c])));
            hT[c * GSTR + r] = fmaxf(h, 0.f);
        }
    }
    __syncthreads();

    const int lane = tid & 63;
    const int wave = tid >> 6;
    const int ng = lane >> 3;
    const int cg = lane & 7;
    const int nodeLoc = wave * 64 + ng * 8;

    float4 acc[8][2];
#pragma unroll
    for (int i = 0; i < 8; ++i) {
        acc[i][0] = make_float4(0.f, 0.f, 0.f, 0.f);
        acc[i][1] = make_float4(0.f, 0.f, 0.f, 0.f);
    }

#pragma unroll 4
    for (int k = 0; k < 64; ++k) {
        const float4* ap = (const float4*)(hT + k * GSTR + nodeLoc);
        const float4* bp = (const float4*)(Ws + k * 64 + cg * 8);
        float4 a0 = ap[0], a1 = ap[1];
        float4 b0v = bp[0], b1v = bp[1];
        const float av[8] = { a0.x, a0.y, a0.z, a0.w, a1.x, a1.y, a1.z, a1.w };
#pragma unroll
        for (int i = 0; i < 8; ++i) {
            acc[i][0].x = fmaf(av[i], b0v.x, acc[i][0].x);
            acc[i][0].y = fmaf(av[i], b0v.y, acc[i][0].y);
            acc[i][0].z = fmaf(av[i], b0v.z, acc[i][0].z);
            acc[i][0].w = fmaf(av[i], b0v.w, acc[i][0].w);
            acc[i][1].x = fmaf(av[i], b1v.x, acc[i][1].x);
            acc[i][1].y = fmaf(av[i], b1v.y, acc[i][1].y);
            acc[i][1].z = fmaf(av[i], b1v.z, acc[i][1].z);
            acc[i][1].w = fmaf(av[i], b1v.w, acc[i][1].w);
        }
    }

#pragma unroll
    for (int i = 0; i < 8; ++i) {
        int row = n0 + nodeLoc + i;
        if (row < n) {
            float dv = dinv[row];
            uint4 pk;
            pk.x = packbf2(acc[i][0].x * dv, acc[i][0].y * dv);
            pk.y = packbf2(acc[i][0].z * dv, acc[i][0].w * dv);
            pk.z = packbf2(acc[i][1].x * dv, acc[i][1].y * dv);
            pk.w = packbf2(acc[i][1].z * dv, acc[i][1].w * dv);
            *(uint4*)(t + (size_t)row * 64 + cg * 8) = pk;
        }
    }
}

// ts(bf16) = (h @ W) * dinv, register-blocked; INPUT h is bf16.
__global__ __launch_bounds__(128) void k_gemm64(const unsigned short* __restrict__ h,
        const float* __restrict__ W, const float* __restrict__ dinv,
        unsigned short* __restrict__ t, int n) {
    __shared__ float hT[64 * GSTR];
    __shared__ float Ws[64 * 64];
    const int tid = threadIdx.x;
    const int n0 = blockIdx.x * GN;

    {
        const float4* W4 = (const float4*)W;
        float4* Ws4 = (float4*)Ws;
        for (int i = tid; i < 1024; i += 128) Ws4[i] = W4[i];
    }
    for (int p = 0; p < 8; ++p) {
        int idx = p * 128 + tid;         // 0..1023 uint4 slots (8 bf16 each)
        int r = idx >> 3;                // local node 0..127
        int c8 = idx & 7;                // group of 8 cols
        int gr = n0 + r;
        uint4 v = (gr < n) ? ((const uint4*)h)[(size_t)gr * 8 + c8]
                           : make_uint4(0u, 0u, 0u, 0u);
        int c = c8 * 8;
        hT[(c + 0) * GSTR + r] = bflo(v.x);
        hT[(c + 1) * GSTR + r] = bfhi(v.x);
        hT[(c + 2) * GSTR + r] = bflo(v.y);
        hT[(c + 3) * GSTR + r] = bfhi(v.y);
        hT[(c + 4) * GSTR + r] = bflo(v.z);
        hT[(c + 5) * GSTR + r] = bfhi(v.z);
        hT[(c + 6) * GSTR + r] = bflo(v.w);
        hT[(c + 7) * GSTR + r] = bfhi(v.w);
    }
    __syncthreads();

    const int lane = tid & 63;
    const int wave = tid >> 6;
    const int ng = lane >> 3;
    const int cg = lane & 7;
    const int nodeLoc = wave * 64 + ng * 8;

    float4 acc[8][2];
#pragma unroll
    for (int i = 0; i < 8; ++i) {
        acc[i][0] = make_float4(0.f, 0.f, 0.f, 0.f);
        acc[i][1] = make_float4(0.f, 0.f, 0.f, 0.f);
    }

#pragma unroll 4
    for (int k = 0; k < 64; ++k) {
        const float4* ap = (const float4*)(hT + k * GSTR + nodeLoc);
        const float4* bp = (const float4*)(Ws + k * 64 + cg * 8);
        float4 a0 = ap[0], a1 = ap[1];
        float4 b0 = bp[0], b1 = bp[1];
        const float av[8] = { a0.x, a0.y, a0.z, a0.w, a1.x, a1.y, a1.z, a1.w };
#pragma unroll
        for (int i = 0; i < 8; ++i) {
            acc[i][0].x = fmaf(av[i], b0.x, acc[i][0].x);
            acc[i][0].y = fmaf(av[i], b0.y, acc[i][0].y);
            acc[i][0].z = fmaf(av[i], b0.z, acc[i][0].z);
            acc[i][0].w = fmaf(av[i], b0.w, acc[i][0].w);
            acc[i][1].x = fmaf(av[i], b1.x, acc[i][1].x);
            acc[i][1].y = fmaf(av[i], b1.y, acc[i][1].y);
            acc[i][1].z = fmaf(av[i], b1.z, acc[i][1].z);
            acc[i][1].w = fmaf(av[i], b1.w, acc[i][1].w);
        }
    }

#pragma unroll
    for (int i = 0; i < 8; ++i) {
        int row = n0 + nodeLoc + i;
        if (row < n) {
            float dv = dinv[row];
            uint4 pk;
            pk.x = packbf2(acc[i][0].x * dv, acc[i][0].y * dv);
            pk.y = packbf2(acc[i][0].z * dv, acc[i][0].w * dv);
            pk.z = packbf2(acc[i][1].x * dv, acc[i][1].y * dv);
            pk.w = packbf2(acc[i][1].z * dv, acc[i][1].w * dv);
            *(uint4*)(t + (size_t)row * 64 + cg * 8) = pk;
        }
    }
}

// h2[n][j] = relu( b[j] + dn*( ts[n][j] + sum_s ts[s][j] ) ), written bf16.
// 8-lane group per node, lane = uint4 (8 bf16 channels), branch-free padded
// chunks of 8; unroll 2 => 16 independent 128B row gathers in flight per group.
__global__ void k_agg(const unsigned short* __restrict__ t, const float* __restrict__ dinv,
                      const int* __restrict__ rowstart, const int* __restrict__ cnt,
                      const int* __restrict__ col,
                      const float* __restrict__ b, unsigned short* __restrict__ out, int n) {
    const int gl  = threadIdx.x & 7;
    const int grp = threadIdx.x >> 3;
    const int gpb = blockDim.x >> 3;
    const float4 bv0 = ((const float4*)b)[gl * 2];
    const float4 bv1 = ((const float4*)b)[gl * 2 + 1];
    for (int node = blockIdx.x * gpb + grp; node < n; node += gpb * gridDim.x) {
        float dn = dinv[node];
        uint4 tv = *(const uint4*)(t + (size_t)node * 64 + gl * 8);
        float a0 = bflo(tv.x), a1 = bfhi(tv.x), a2 = bflo(tv.y), a3 = bfhi(tv.y);
        float a4 = bflo(tv.z), a5 = bfhi(tv.z), a6 = bflo(tv.w), a7 = bfhi(tv.w);
        int s0 = rowstart[node];
        int cpad = (cnt[node] + 7) & ~7;
#pragma unroll 2
        for (int base = 0; base < cpad; base += 8) {
            int myidx = col[s0 + base + gl];
#pragma unroll
            for (int j = 0; j < 8; ++j) {
                int s = __shfl(myidx, j, 8);
                uint4 g = *(const uint4*)(t + (size_t)s * 64 + gl * 8);
                a0 += bflo(g.x); a1 += bfhi(g.x);
                a2 += bflo(g.y); a3 += bfhi(g.y);
                a4 += bflo(g.z); a5 += bfhi(g.z);
                a6 += bflo(g.w); a7 += bfhi(g.w);
            }
        }
        uint4 o;
        o.x = packbf2(fmaxf(fmaf(a0, dn, bv0.x), 0.f), fmaxf(fmaf(a1, dn, bv0.y), 0.f));
        o.y = packbf2(fmaxf(fmaf(a2, dn, bv0.z), 0.f), fmaxf(fmaf(a3, dn, bv0.w), 0.f));
        o.z = packbf2(fmaxf(fmaf(a4, dn, bv1.x), 0.f), fmaxf(fmaf(a5, dn, bv1.y), 0.f));
        o.w = packbf2(fmaxf(fmaf(a6, dn, bv1.z), 0.f), fmaxf(fmaf(a7, dn, bv1.w), 0.f));
        *(uint4*)(out + (size_t)node * 64 + gl * 8) = o;
    }
}

// Final layer fused with output head:
// h3[j] = relu( b2[j] + dn*(ts[n][j] + sum ts[s][j]) ); out[n] = sigmoid(h3·Wo + bo)
__global__ void k_agg_out(const unsigned short* __restrict__ t, const float* __restrict__ dinv,
                          const int* __restrict__ rowstart, const int* __restrict__ cnt,
                          const int* __restrict__ col,
                          const float* __restrict__ b, const float* __restrict__ Wo,
                          const float* __restrict__ bo, float* __restrict__ out, int n) {
    const int gl  = threadIdx.x & 7;
    const int grp = threadIdx.x >> 3;
    const int gpb = blockDim.x >> 3;
    const float4 bv0 = ((const float4*)b)[gl * 2];
    const float4 bv1 = ((const float4*)b)[gl * 2 + 1];
    const float4 wv0 = ((const float4*)Wo)[gl * 2];
    const float4 wv1 = ((const float4*)Wo)[gl * 2 + 1];
    const float bo0 = bo[0];
    for (int node = blockIdx.x * gpb + grp; node < n; node += gpb * gridDim.x) {
        float dn = dinv[node];
        uint4 tv = *(const uint4*)(t + (size_t)node * 64 + gl * 8);
        float a0 = bflo(tv.x), a1 = bfhi(tv.x), a2 = bflo(tv.y), a3 = bfhi(tv.y);
        float a4 = bflo(tv.z), a5 = bfhi(tv.z), a6 = bflo(tv.w), a7 = bfhi(tv.w);
        int s0 = rowstart[node];
        int cpad = (cnt[node] + 7) & ~7;
#pragma unroll 2
        for (int base = 0; base < cpad; base += 8) {
            int myidx = col[s0 + base + gl];
#pragma unroll
            for (int j = 0; j < 8; ++j) {
                int s = __shfl(myidx, j, 8);
                uint4 g = *(const uint4*)(t + (size_t)s * 64 + gl * 8);
                a0 += bflo(g.x); a1 += bfhi(g.x);
                a2 += bflo(g.y); a3 += bfhi(g.y);
                a4 += bflo(g.z); a5 += bfhi(g.z);
                a6 += bflo(g.w); a7 += bfhi(g.w);
            }
        }
        float v = fmaxf(fmaf(a0, dn, bv0.x), 0.f) * wv0.x
                + fmaxf(fmaf(a1, dn, bv0.y), 0.f) * wv0.y
                + fmaxf(fmaf(a2, dn, bv0.z), 0.f) * wv0.z
                + fmaxf(fmaf(a3, dn, bv0.w), 0.f) * wv0.w
                + fmaxf(fmaf(a4, dn, bv1.x), 0.f) * wv1.x
                + fmaxf(fmaf(a5, dn, bv1.y), 0.f) * wv1.y
                + fmaxf(fmaf(a6, dn, bv1.z), 0.f) * wv1.z
                + fmaxf(fmaf(a7, dn, bv1.w), 0.f) * wv1.w;
#pragma unroll
        for (int off = 4; off > 0; off >>= 1) v += __shfl_xor(v, off, 8);
        if (gl == 0) out[node] = 1.0f / (1.0f + expf(-(v + bo0)));
    }
}

// ---------------- launch ----------------

extern "C" void kernel_launch(void* const* d_in, const int* in_sizes, int n_in,
                              void* d_out, int out_size, void* d_ws, size_t ws_size,
                              hipStream_t stream) {
    const float* x  = (const float*)d_in[0];
    const int*   ei = (const int*)d_in[1];
    const float* W0 = (const float*)d_in[2];
    const float* b0 = (const float*)d_in[3];
    const float* W1 = (const float*)d_in[4];
    const float* b1 = (const float*)d_in[5];
    const float* W2 = (const float*)d_in[6];
    const float* b2 = (const float*)d_in[7];
    const float* Wo = (const float*)d_in[8];
    const float* bo = (const float*)d_in[9];
    float* out = (float*)d_out;

    const int N = in_sizes[0] / 3;
    const int E = in_sizes[1] / 2;
    const int* src = ei;
    const int* dst = ei + E;
    const int nb = (N + VPB - 1) >> VSH;

    char* w = (char*)d_ws;
    size_t off = 0;
    auto take = [&](size_t bytes) -> void* {
        void* p = w + off;
        off = (off + bytes + 255) & ~(size_t)255;
        return p;
    };
    float* dinv     = (float*)take((size_t)N * 4);
    int*   cnt      = (int*)take((size_t)N * 4);
    int*   rowstart = (int*)take((size_t)N * 4);
    int*   gtotal   = (int*)take(4);
    int*   bktCur   = (int*)take(MAXB * 4);
    float* xw       = (float*)take((size_t)(N + 1) * 3 * 4);      // +sentinel row
    float* xa       = (float*)take((size_t)N * 3 * 4);
    int*   col      = (int*)take(((size_t)E + 8 * (size_t)N) * 4); // padded CSR
    unsigned short* A = (unsigned short*)take((size_t)(N + 1) * 64 * 2); // bf16 (+sentinel)
    unsigned short* B = (unsigned short*)take((size_t)N * 64 * 2);       // bf16 h
    int*   binned   = (int*)take((size_t)MAXB * CAP * 4);
    (void)ws_size; (void)n_in; (void)out_size;

    const int TB = 256;
    // graph prep: bin -> per-bucket padded CSR build (also emits dinv + xw)
    k_zero  <<<1, 256, 0, stream>>>(bktCur, gtotal, A + (size_t)N * 64, xw + (size_t)N * 3);
    k_bin   <<<(E + BINCH - 1) / BINCH, TB, 0, stream>>>(src, dst, bktCur, binned, E, nb);
    k_bucket<<<nb, VPB, 0, stream>>>(binned, bktCur, gtotal, rowstart, cnt, dinv, col, x, xw, N);

    // layer 0 agg (3-dim, pre-weighted payload, 4-lane groups)
    k_agg3  <<<2048, TB, 0, stream>>>(xw, dinv, rowstart, cnt, col, xa, N);
    // layer 1: fused h0-compute + GEMM W1 + dinv-scale -> bf16 A
    k_l1    <<<(N + GN - 1) / GN, 128, 0, stream>>>(xa, W0, b0, W1, dinv, A, N);
    k_agg   <<<2048, TB, 0, stream>>>(A, dinv, rowstart, cnt, col, b1, B, N);
    // layer 2 (bf16 in, bf16 out)
    k_gemm64<<<(N + GN - 1) / GN, 128, 0, stream>>>(B, W2, dinv, A, N);
    k_agg_out<<<2048, TB, 0, stream>>>(A, dinv, rowstart, cnt, col, b2, Wo, bo, out, N);
}

// Round 14
// 167.956 us; speedup vs baseline: 1.5090x; 1.0412x over previous
//
#include <hip/hip_runtime.h>
#include <math.h>

// Graph constants for this problem size (N=100000, E=1600000).
#define VSH   9                  // nodes per bucket = 512
#define VPB   512
#define MAXB  256                // max buckets (N <= 131072)
#define CAP   12288              // per-bucket edge capacity (padded)
#define BINCH 8192               // edges per k_bin block

// GEMM tiling
#define GN    128                // nodes per block
#define GSTR  132                // hT row stride in floats (16B-aligned; 2-way banks)

// ---------------- bf16 helpers (RNE) ----------------
__device__ __forceinline__ float bflo(unsigned u) { return __uint_as_float(u << 16); }
__device__ __forceinline__ float bfhi(unsigned u) { return __uint_as_float(u & 0xFFFF0000u); }
__device__ __forceinline__ unsigned packbf2(float a, float b) {
    unsigned ua = __float_as_uint(a);
    unsigned ub = __float_as_uint(b);
    ua += 0x7FFFu + ((ua >> 16) & 1u);   // round-to-nearest-even
    ub += 0x7FFFu + ((ub >> 16) & 1u);
    return (ua >> 16) | (ub & 0xFFFF0000u);
}

// ---------------- graph prep ----------------

// zero counters + the sentinel rows (node id == n) of A, A2 and xw
__global__ void k_zero(int* __restrict__ bktCur, int* __restrict__ gtotal,
                       unsigned short* __restrict__ tz, unsigned short* __restrict__ tz2,
                       float* __restrict__ xwz) {
    int i = threadIdx.x;
    if (i < MAXB) bktCur[i] = 0;
    if (i == 0) *gtotal = 0;
    if (i < 64) { tz[i] = 0; tz2[i] = 0; }
    if (i < 3) xwz[i] = 0.f;
}

// Bin edges by dst bucket. Per block: LDS histogram -> per-bucket global
// reservation -> LDS stage ordered by bucket -> coalesced write-out.
__global__ void k_bin(const int* __restrict__ src, const int* __restrict__ dst,
                      int* __restrict__ bktCur, int* __restrict__ binned,
                      int e, int nb) {
    __shared__ int hist[MAXB];
    __shared__ int offs[MAXB];
    __shared__ int gbase[MAXB];
    __shared__ int lcur[MAXB];
    __shared__ int stage[BINCH];
    __shared__ unsigned char binid[BINCH];
    const int tid = threadIdx.x;
    const int blockStart = blockIdx.x * BINCH;
    const int chunk = min(BINCH, e - blockStart);

    for (int b = tid; b < MAXB; b += blockDim.x) hist[b] = 0;
    __syncthreads();

    // pass 1: histogram
    for (int k = 0; k < BINCH / 1024; ++k) {
        int i0 = blockStart + k * 1024 + tid * 4;
        if (i0 + 3 < e) {
            int4 d4 = *(const int4*)(dst + i0);
            atomicAdd(&hist[d4.x >> VSH], 1);
            atomicAdd(&hist[d4.y >> VSH], 1);
            atomicAdd(&hist[d4.z >> VSH], 1);
            atomicAdd(&hist[d4.w >> VSH], 1);
        } else {
            for (int i = i0; i < e && i < i0 + 4; ++i)
                atomicAdd(&hist[dst[i] >> VSH], 1);
        }
    }
    __syncthreads();

    if (tid == 0) {
        int run = 0;
        for (int b = 0; b < nb; ++b) { offs[b] = run; run += hist[b]; }
    }
    __syncthreads();
    if (tid < nb) {
        gbase[tid] = (hist[tid] > 0) ? atomicAdd(&bktCur[tid], hist[tid]) : 0;
        lcur[tid] = offs[tid];
    }
    __syncthreads();

    // pass 2: stage ordered by bucket (re-read edges, L2-hot)
    for (int k = 0; k < BINCH / 1024; ++k) {
        int i0 = blockStart + k * 1024 + tid * 4;
        if (i0 + 3 < e) {
            int4 s4 = *(const int4*)(src + i0);
            int4 d4 = *(const int4*)(dst + i0);
            int bs[4] = { d4.x >> VSH, d4.y >> VSH, d4.z >> VSH, d4.w >> VSH };
            int pk[4] = { ((d4.x & (VPB - 1)) << 17) | s4.x,
                          ((d4.y & (VPB - 1)) << 17) | s4.y,
                          ((d4.z & (VPB - 1)) << 17) | s4.z,
                          ((d4.w & (VPB - 1)) << 17) | s4.w };
#pragma unroll
            for (int q = 0; q < 4; ++q) {
                int slot = atomicAdd(&lcur[bs[q]], 1);
                stage[slot] = pk[q];
                binid[slot] = (unsigned char)bs[q];
            }
        } else {
            for (int i = i0; i < e && i < i0 + 4; ++i) {
                int d = dst[i], b = d >> VSH;
                int slot = atomicAdd(&lcur[b], 1);
                stage[slot] = ((d & (VPB - 1)) << 17) | src[i];
                binid[slot] = (unsigned char)b;
            }
        }
    }
    __syncthreads();

    // pass 3: coalesced write-out per bucket run
    for (int j = tid; j < chunk; j += blockDim.x) {
        int b = binid[j];
        int idx = gbase[b] + (j - offs[b]);
        if (idx < CAP) binned[b * CAP + idx] = stage[j];
    }
}

// One block per bucket: LDS histogram (-> deg/cnt/dinv), PADDED LDS scan
// (segments rounded up to multiples of 8, filler = sentinel node n), one atomic
// for the bucket CSR base, LDS scatter, coalesced col write-out.
// Also emits xw[nid] = x[nid]*dinv[nid].
__global__ void k_bucket(const int* __restrict__ binned, const int* __restrict__ bktCur,
                         int* __restrict__ gtotal, int* __restrict__ rowstart,
                         int* __restrict__ cntG, float* __restrict__ dinv,
                         int* __restrict__ col, const float* __restrict__ x,
                         float* __restrict__ xw, int n) {
    __shared__ int buf[VPB];
    __shared__ int cur[VPB];
    __shared__ int colStage[CAP];
    __shared__ int sBase;
    const int tid = threadIdx.x;                 // blockDim = VPB
    const int b = blockIdx.x;
    const int nodeBase = b << VSH;
    const int count = min(bktCur[b], CAP);
    const int* bb = binned + b * CAP;

    buf[tid] = 0;
    __syncthreads();
    for (int i = tid; i < count; i += VPB)
        atomicAdd(&buf[bb[i] >> 17], 1);
    __syncthreads();
    int v = buf[tid];                            // real degree
    int vpad = (v + 7) & ~7;                     // padded segment length
    buf[tid] = vpad;
    __syncthreads();
    for (int off = 1; off < VPB; off <<= 1) {
        int t = (tid >= off) ? buf[tid - off] : 0;
        __syncthreads();
        buf[tid] += t;
        __syncthreads();
    }
    int excl = buf[tid] - vpad;
    if (tid == 0) sBase = atomicAdd(gtotal, buf[VPB - 1]);
    __syncthreads();
    int totalPad = buf[VPB - 1];
    int base = sBase;
    int nid = nodeBase + tid;
    if (nid < n) {
        float dv = rsqrtf((float)v + 1.0f);
        rowstart[nid] = base + excl;
        cntG[nid] = v;
        dinv[nid] = dv;
        const float* xr = x + (size_t)nid * 3;
        float* xo = xw + (size_t)nid * 3;
        xo[0] = xr[0] * dv;
        xo[1] = xr[1] * dv;
        xo[2] = xr[2] * dv;
    }
    cur[tid] = excl;
    for (int j = tid; j < totalPad && j < CAP; j += VPB) colStage[j] = n;
    __syncthreads();
    for (int i = tid; i < count; i += VPB) {
        int p = bb[i];
        int slot = atomicAdd(&cur[p >> 17], 1);
        colStage[slot] = p & 0x1FFFF;
    }
    __syncthreads();
    for (int j = tid; j < totalPad && j < CAP; j += VPB)
        col[base + j] = colStage[j];
}

// ---------------- layers ----------------

// Layer-0: aggregation commutes with the GEMM; payload xw = x*dinv pre-weighted.
__global__ void k_agg3(const float* __restrict__ xw, const float* __restrict__ dinv,
                       const int* __restrict__ rowstart, const int* __restrict__ cnt,
                       const int* __restrict__ col, float* __restrict__ xa, int n) {
    const int gl  = threadIdx.x & 3;
    const int grp = threadIdx.x >> 2;
    const int gpb = blockDim.x >> 2;
    for (int node = blockIdx.x * gpb + grp; node < n; node += gpb * gridDim.x) {
        float dn = dinv[node];
        float a = (gl < 3) ? xw[(size_t)node * 3 + gl] : 0.f;
        int s0 = rowstart[node];
        int cpad = (cnt[node] + 7) & ~7;
        for (int base = 0; base < cpad; base += 4) {
            int myidx = col[s0 + base + gl];
#pragma unroll
            for (int j = 0; j < 4; ++j) {
                int s = __shfl(myidx, j, 4);
                if (gl < 3) a += xw[(size_t)s * 3 + gl];   // sentinel row is zeros
            }
        }
        if (gl < 3) xa[(size_t)node * 3 + gl] = a * dn;
    }
}

// Fused layer-1 GEMM: t1s = ( relu(xa@W0 + b0) @ W1 ) * dinv, bf16 out.
__global__ __launch_bounds__(128) void k_l1(const float* __restrict__ xa,
        const float* __restrict__ W0, const float* __restrict__ b0,
        const float* __restrict__ W1, const float* __restrict__ dinv,
        unsigned short* __restrict__ t, int n) {
    __shared__ float hT[64 * GSTR];      // [k][node], stride GSTR
    __shared__ float Ws[64 * 64];        // [k][j] = W1
    __shared__ float W0s[3 * 64];
    __shared__ float b0s[64];
    __shared__ float xas[GN * 3];
    const int tid = threadIdx.x;
    const int n0 = blockIdx.x * GN;

    {
        const float4* W4 = (const float4*)W1;
        float4* Ws4 = (float4*)Ws;
        for (int i = tid; i < 1024; i += 128) Ws4[i] = W4[i];
    }
    if (tid < 64) b0s[tid] = b0[tid];
    for (int i = tid; i < 192; i += 128) W0s[i] = W0[i];
    for (int i = tid; i < GN * 3; i += 128) {
        int gi = n0 * 3 + i;
        xas[i] = (gi < n * 3) ? xa[gi] : 0.f;
    }
    __syncthreads();

    for (int p = 0; p < 16; ++p) {
        int idx = p * 128 + tid;
        int r = idx >> 4;
        int c4 = idx & 15;
        float x0 = xas[r * 3 + 0], x1 = xas[r * 3 + 1], x2 = xas[r * 3 + 2];
#pragma unroll
        for (int q = 0; q < 4; ++q) {
            int c = c4 * 4 + q;
            float h = fmaf(x0, W0s[c], fmaf(x1, W0s[64 + c], fmaf(x2, W0s[128 + c], b0s[c])));
            hT[c * GSTR + r] = fmaxf(h, 0.f);
        }
    }
    __syncthreads();

    const int lane = tid & 63;
    const int wave = tid >> 6;
    const int ng = lane >> 3;
    const int cg = lane & 7;
    const int nodeLoc = wave * 64 + ng * 8;

    float4 acc[8][2];
#pragma unroll
    for (int i = 0; i < 8; ++i) {
        acc[i][0] = make_float4(0.f, 0.f, 0.f, 0.f);
        acc[i][1] = make_float4(0.f, 0.f, 0.f, 0.f);
    }

#pragma unroll 4
    for (int k = 0; k < 64; ++k) {
        const float4* ap = (const float4*)(hT + k * GSTR + nodeLoc);
        const float4* bp = (const float4*)(Ws + k * 64 + cg * 8);
        float4 a0 = ap[0], a1 = ap[1];
        float4 b0v = bp[0], b1v = bp[1];
        const float av[8] = { a0.x, a0.y, a0.z, a0.w, a1.x, a1.y, a1.z, a1.w };
#pragma unroll
        for (int i = 0; i < 8; ++i) {
            acc[i][0].x = fmaf(av[i], b0v.x, acc[i][0].x);
            acc[i][0].y = fmaf(av[i], b0v.y, acc[i][0].y);
            acc[i][0].z = fmaf(av[i], b0v.z, acc[i][0].z);
            acc[i][0].w = fmaf(av[i], b0v.w, acc[i][0].w);
            acc[i][1].x = fmaf(av[i], b1v.x, acc[i][1].x);
            acc[i][1].y = fmaf(av[i], b1v.y, acc[i][1].y);
            acc[i][1].z = fmaf(av[i], b1v.z, acc[i][1].z);
            acc[i][1].w = fmaf(av[i], b1v.w, acc[i][1].w);
        }
    }

#pragma unroll
    for (int i = 0; i < 8; ++i) {
        int row = n0 + nodeLoc + i;
        if (row < n) {
            float dv = dinv[row];
            uint4 pk;
            pk.x = packbf2(acc[i][0].x * dv, acc[i][0].y * dv);
            pk.y = packbf2(acc[i][0].z * dv, acc[i][0].w * dv);
            pk.z = packbf2(acc[i][1].x * dv, acc[i][1].y * dv);
            pk.w = packbf2(acc[i][1].z * dv, acc[i][1].w * dv);
            *(uint4*)(t + (size_t)row * 64 + cg * 8) = pk;
        }
    }
}

// FUSED layer-1 aggregation + layer-2 GEMM:
//   h2[r][j] = relu(b1[j] + dn*(t1s[r][j] + sum_s t1s[s][j]))   (phase A -> hT fp32)
//   t2s = (h2 @ W2) * dinv, bf16 out                            (phase B)
// B (h2) is never materialized in global memory.
__global__ __launch_bounds__(256) void k_aggemm(const unsigned short* __restrict__ t,
        const float* __restrict__ dinv, const int* __restrict__ rowstart,
        const int* __restrict__ cnt, const int* __restrict__ col,
        const float* __restrict__ b, const float* __restrict__ W,
        unsigned short* __restrict__ out, int n) {
    __shared__ float hT[64 * GSTR];      // [channel][node]
    __shared__ float Ws[64 * 64];        // [k][j] = W2
    const int tid = threadIdx.x;
    const int n0 = blockIdx.x * GN;

    // stage W2
    {
        const float4* W4 = (const float4*)W;
        float4* Ws4 = (float4*)Ws;
        for (int i = tid; i < 1024; i += 256) Ws4[i] = W4[i];
    }

    // phase A: aggregate 128 node rows -> hT (transposed, fp32, relu+bias applied)
    {
        const int gl  = tid & 7;          // lane in group (8 bf16 channels)
        const int grp = tid >> 3;         // 32 groups
        const float4 bv0 = ((const float4*)b)[gl * 2];
        const float4 bv1 = ((const float4*)b)[gl * 2 + 1];
#pragma unroll
        for (int i = 0; i < 4; ++i) {
            int r = grp * 4 + i;          // local node 0..127
            int node = n0 + r;
            float h0 = 0.f, h1 = 0.f, h2 = 0.f, h3 = 0.f;
            float h4 = 0.f, h5 = 0.f, h6 = 0.f, h7 = 0.f;
            if (node < n) {
                float dn = dinv[node];
                uint4 tv = *(const uint4*)(t + (size_t)node * 64 + gl * 8);
                float a0 = bflo(tv.x), a1 = bfhi(tv.x), a2 = bflo(tv.y), a3 = bfhi(tv.y);
                float a4 = bflo(tv.z), a5 = bfhi(tv.z), a6 = bflo(tv.w), a7 = bfhi(tv.w);
                int s0 = rowstart[node];
                int cpad = (cnt[node] + 7) & ~7;
                for (int base = 0; base < cpad; base += 8) {
                    int myidx = col[s0 + base + gl];
#pragma unroll
                    for (int j = 0; j < 8; ++j) {
                        int s = __shfl(myidx, j, 8);
                        uint4 g = *(const uint4*)(t + (size_t)s * 64 + gl * 8);
                        a0 += bflo(g.x); a1 += bfhi(g.x);
                        a2 += bflo(g.y); a3 += bfhi(g.y);
                        a4 += bflo(g.z); a5 += bfhi(g.z);
                        a6 += bflo(g.w); a7 += bfhi(g.w);
                    }
                }
                h0 = fmaxf(fmaf(a0, dn, bv0.x), 0.f);
                h1 = fmaxf(fmaf(a1, dn, bv0.y), 0.f);
                h2 = fmaxf(fmaf(a2, dn, bv0.z), 0.f);
                h3 = fmaxf(fmaf(a3, dn, bv0.w), 0.f);
                h4 = fmaxf(fmaf(a4, dn, bv1.x), 0.f);
                h5 = fmaxf(fmaf(a5, dn, bv1.y), 0.f);
                h6 = fmaxf(fmaf(a6, dn, bv1.z), 0.f);
                h7 = fmaxf(fmaf(a7, dn, bv1.w), 0.f);
            }
            int c = gl * 8;
            hT[(c + 0) * GSTR + r] = h0;
            hT[(c + 1) * GSTR + r] = h1;
            hT[(c + 2) * GSTR + r] = h2;
            hT[(c + 3) * GSTR + r] = h3;
            hT[(c + 4) * GSTR + r] = h4;
            hT[(c + 5) * GSTR + r] = h5;
            hT[(c + 6) * GSTR + r] = h6;
            hT[(c + 7) * GSTR + r] = h7;
        }
    }
    __syncthreads();

    // phase B: GEMM from LDS. 4 waves; thread tile = 4 nodes x 8 cols.
    const int lane = tid & 63;
    const int wave = tid >> 6;           // 0..3
    const int ng = lane >> 3;            // 0..7
    const int cg = lane & 7;             // 0..7
    const int nodeLoc = wave * 32 + ng * 4;

    float4 acc[4][2];
#pragma unroll
    for (int i = 0; i < 4; ++i) {
        acc[i][0] = make_float4(0.f, 0.f, 0.f, 0.f);
        acc[i][1] = make_float4(0.f, 0.f, 0.f, 0.f);
    }

#pragma unroll 4
    for (int k = 0; k < 64; ++k) {
        float4 a = *(const float4*)(hT + k * GSTR + nodeLoc);
        const float4* bp = (const float4*)(Ws + k * 64 + cg * 8);
        float4 b0 = bp[0], b1 = bp[1];
        const float av[4] = { a.x, a.y, a.z, a.w };
#pragma unroll
        for (int i = 0; i < 4; ++i) {
            acc[i][0].x = fmaf(av[i], b0.x, acc[i][0].x);
            acc[i][0].y = fmaf(av[i], b0.y, acc[i][0].y);
            acc[i][0].z = fmaf(av[i], b0.z, acc[i][0].z);
            acc[i][0].w = fmaf(av[i], b0.w, acc[i][0].w);
            acc[i][1].x = fmaf(av[i], b1.x, acc[i][1].x);
            acc[i][1].y = fmaf(av[i], b1.y, acc[i][1].y);
            acc[i][1].z = fmaf(av[i], b1.z, acc[i][1].z);
            acc[i][1].w = fmaf(av[i], b1.w, acc[i][1].w);
        }
    }

#pragma unroll
    for (int i = 0; i < 4; ++i) {
        int row = n0 + nodeLoc + i;
        if (row < n) {
            float dv = dinv[row];
            uint4 pk;
            pk.x = packbf2(acc[i][0].x * dv, acc[i][0].y * dv);
            pk.y = packbf2(acc[i][0].z * dv, acc[i][0].w * dv);
            pk.z = packbf2(acc[i][1].x * dv, acc[i][1].y * dv);
            pk.w = packbf2(acc[i][1].z * dv, acc[i][1].w * dv);
            *(uint4*)(out + (size_t)row * 64 + cg * 8) = pk;
        }
    }
}

// Final layer fused with output head:
// h3[j] = relu( b2[j] + dn*(ts[n][j] + sum ts[s][j]) ); out[n] = sigmoid(h3·Wo + bo)
__global__ void k_agg_out(const unsigned short* __restrict__ t, const float* __restrict__ dinv,
                          const int* __restrict__ rowstart, const int* __restrict__ cnt,
                          const int* __restrict__ col,
                          const float* __restrict__ b, const float* __restrict__ Wo,
                          const float* __restrict__ bo, float* __restrict__ out, int n) {
    const int gl  = threadIdx.x & 7;
    const int grp = threadIdx.x >> 3;
    const int gpb = blockDim.x >> 3;
    const float4 bv0 = ((const float4*)b)[gl * 2];
    const float4 bv1 = ((const float4*)b)[gl * 2 + 1];
    const float4 wv0 = ((const float4*)Wo)[gl * 2];
    const float4 wv1 = ((const float4*)Wo)[gl * 2 + 1];
    const float bo0 = bo[0];
    for (int node = blockIdx.x * gpb + grp; node < n; node += gpb * gridDim.x) {
        float dn = dinv[node];
        uint4 tv = *(const uint4*)(t + (size_t)node * 64 + gl * 8);
        float a0 = bflo(tv.x), a1 = bfhi(tv.x), a2 = bflo(tv.y), a3 = bfhi(tv.y);
        float a4 = bflo(tv.z), a5 = bfhi(tv.z), a6 = bflo(tv.w), a7 = bfhi(tv.w);
        int s0 = rowstart[node];
        int cpad = (cnt[node] + 7) & ~7;
        for (int base = 0; base < cpad; base += 8) {
            int myidx = col[s0 + base + gl];
#pragma unroll
            for (int j = 0; j < 8; ++j) {
                int s = __shfl(myidx, j, 8);
                uint4 g = *(const uint4*)(t + (size_t)s * 64 + gl * 8);
                a0 += bflo(g.x); a1 += bfhi(g.x);
                a2 += bflo(g.y); a3 += bfhi(g.y);
                a4 += bflo(g.z); a5 += bfhi(g.z);
                a6 += bflo(g.w); a7 += bfhi(g.w);
            }
        }
        float v = fmaxf(fmaf(a0, dn, bv0.x), 0.f) * wv0.x
                + fmaxf(fmaf(a1, dn, bv0.y), 0.f) * wv0.y
                + fmaxf(fmaf(a2, dn, bv0.z), 0.f) * wv0.z
                + fmaxf(fmaf(a3, dn, bv0.w), 0.f) * wv0.w
                + fmaxf(fmaf(a4, dn, bv1.x), 0.f) * wv1.x
                + fmaxf(fmaf(a5, dn, bv1.y), 0.f) * wv1.y
                + fmaxf(fmaf(a6, dn, bv1.z), 0.f) * wv1.z
                + fmaxf(fmaf(a7, dn, bv1.w), 0.f) * wv1.w;
#pragma unroll
        for (int off = 4; off > 0; off >>= 1) v += __shfl_xor(v, off, 8);
        if (gl == 0) out[node] = 1.0f / (1.0f + expf(-(v + bo0)));
    }
}

// ---------------- launch ----------------

extern "C" void kernel_launch(void* const* d_in, const int* in_sizes, int n_in,
                              void* d_out, int out_size, void* d_ws, size_t ws_size,
                              hipStream_t stream) {
    const float* x  = (const float*)d_in[0];
    const int*   ei = (const int*)d_in[1];
    const float* W0 = (const float*)d_in[2];
    const float* b0 = (const float*)d_in[3];
    const float* W1 = (const float*)d_in[4];
    const float* b1 = (const float*)d_in[5];
    const float* W2 = (const float*)d_in[6];
    const float* b2 = (const float*)d_in[7];
    const float* Wo = (const float*)d_in[8];
    const float* bo = (const float*)d_in[9];
    float* out = (float*)d_out;

    const int N = in_sizes[0] / 3;
    const int E = in_sizes[1] / 2;
    const int* src = ei;
    const int* dst = ei + E;
    const int nb = (N + VPB - 1) >> VSH;

    char* w = (char*)d_ws;
    size_t off = 0;
    auto take = [&](size_t bytes) -> void* {
        void* p = w + off;
        off = (off + bytes + 255) & ~(size_t)255;
        return p;
    };
    float* dinv     = (float*)take((size_t)N * 4);
    int*   cnt      = (int*)take((size_t)N * 4);
    int*   rowstart = (int*)take((size_t)N * 4);
    int*   gtotal   = (int*)take(4);
    int*   bktCur   = (int*)take(MAXB * 4);
    float* xw       = (float*)take((size_t)(N + 1) * 3 * 4);      // +sentinel row
    float* xa       = (float*)take((size_t)N * 3 * 4);
    int*   col      = (int*)take(((size_t)E + 8 * (size_t)N) * 4); // padded CSR
    unsigned short* A  = (unsigned short*)take((size_t)(N + 1) * 64 * 2); // bf16 t1s (+sentinel)
    unsigned short* A2 = (unsigned short*)take((size_t)(N + 1) * 64 * 2); // bf16 t2s (+sentinel)
    int*   binned   = (int*)take((size_t)MAXB * CAP * 4);
    (void)ws_size; (void)n_in; (void)out_size;

    const int TB = 256;
    // graph prep: bin -> per-bucket padded CSR build (also emits dinv + xw)
    k_zero  <<<1, 256, 0, stream>>>(bktCur, gtotal, A + (size_t)N * 64,
                                    A2 + (size_t)N * 64, xw + (size_t)N * 3);
    k_bin   <<<(E + BINCH - 1) / BINCH, TB, 0, stream>>>(src, dst, bktCur, binned, E, nb);
    k_bucket<<<nb, VPB, 0, stream>>>(binned, bktCur, gtotal, rowstart, cnt, dinv, col, x, xw, N);

    // layer 0 agg (3-dim, pre-weighted payload, 4-lane groups)
    k_agg3  <<<2048, TB, 0, stream>>>(xw, dinv, rowstart, cnt, col, xa, N);
    // layer 1: fused h0-compute + GEMM W1 + dinv-scale -> bf16 A
    k_l1    <<<(N + GN - 1) / GN, 128, 0, stream>>>(xa, W0, b0, W1, dinv, A, N);
    // FUSED: layer-1 aggregation + layer-2 GEMM -> bf16 A2 (B never materialized)
    k_aggemm<<<(N + GN - 1) / GN, 256, 0, stream>>>(A, dinv, rowstart, cnt, col,
                                                    b1, W2, A2, N);
    // layer-2 aggregation + output head
    k_agg_out<<<2048, TB, 0, stream>>>(A2, dinv, rowstart, cnt, col, b2, Wo, bo, out, N);
}

// Round 15
// 156.913 us; speedup vs baseline: 1.6152x; 1.0704x over previous
//
#include <hip/hip_runtime.h>
#include <math.h>

// Graph constants for this problem size (N=100000, E=1600000).
#define VSH   9                  // nodes per bucket = 512
#define VPB   512
#define MAXB  256                // max buckets (N <= 131072)
#define CAP   12288              // per-bucket edge capacity (padded)
#define BINCH 8192               // edges per k_bin block

// GEMM tiling
#define GN    128                // nodes per block (k_l1)
#define GSTR  132                // hT row stride in floats (16B-aligned; 2-way banks)
#define GN2   64                 // nodes per block (k_aggemm)
#define PSTR  68                 // hP pair-row stride in unsigned (16B-aligned)

// ---------------- bf16 helpers (RNE) ----------------
__device__ __forceinline__ float bflo(unsigned u) { return __uint_as_float(u << 16); }
__device__ __forceinline__ float bfhi(unsigned u) { return __uint_as_float(u & 0xFFFF0000u); }
__device__ __forceinline__ unsigned packbf2(float a, float b) {
    unsigned ua = __float_as_uint(a);
    unsigned ub = __float_as_uint(b);
    ua += 0x7FFFu + ((ua >> 16) & 1u);   // round-to-nearest-even
    ub += 0x7FFFu + ((ub >> 16) & 1u);
    return (ua >> 16) | (ub & 0xFFFF0000u);
}

// ---------------- graph prep ----------------

// zero counters + the sentinel rows (node id == n) of A, A2 and xw
__global__ void k_zero(int* __restrict__ bktCur, int* __restrict__ gtotal,
                       unsigned short* __restrict__ tz, unsigned short* __restrict__ tz2,
                       float* __restrict__ xwz) {
    int i = threadIdx.x;
    if (i < MAXB) bktCur[i] = 0;
    if (i == 0) *gtotal = 0;
    if (i < 64) { tz[i] = 0; tz2[i] = 0; }
    if (i < 3) xwz[i] = 0.f;
}

// Bin edges by dst bucket. Per block: LDS histogram -> per-bucket global
// reservation -> LDS stage ordered by bucket -> coalesced write-out.
__global__ void k_bin(const int* __restrict__ src, const int* __restrict__ dst,
                      int* __restrict__ bktCur, int* __restrict__ binned,
                      int e, int nb) {
    __shared__ int hist[MAXB];
    __shared__ int offs[MAXB];
    __shared__ int gbase[MAXB];
    __shared__ int lcur[MAXB];
    __shared__ int stage[BINCH];
    __shared__ unsigned char binid[BINCH];
    const int tid = threadIdx.x;
    const int blockStart = blockIdx.x * BINCH;
    const int chunk = min(BINCH, e - blockStart);

    for (int b = tid; b < MAXB; b += blockDim.x) hist[b] = 0;
    __syncthreads();

    // pass 1: histogram
    for (int k = 0; k < BINCH / 1024; ++k) {
        int i0 = blockStart + k * 1024 + tid * 4;
        if (i0 + 3 < e) {
            int4 d4 = *(const int4*)(dst + i0);
            atomicAdd(&hist[d4.x >> VSH], 1);
            atomicAdd(&hist[d4.y >> VSH], 1);
            atomicAdd(&hist[d4.z >> VSH], 1);
            atomicAdd(&hist[d4.w >> VSH], 1);
        } else {
            for (int i = i0; i < e && i < i0 + 4; ++i)
                atomicAdd(&hist[dst[i] >> VSH], 1);
        }
    }
    __syncthreads();

    if (tid == 0) {
        int run = 0;
        for (int b = 0; b < nb; ++b) { offs[b] = run; run += hist[b]; }
    }
    __syncthreads();
    if (tid < nb) {
        gbase[tid] = (hist[tid] > 0) ? atomicAdd(&bktCur[tid], hist[tid]) : 0;
        lcur[tid] = offs[tid];
    }
    __syncthreads();

    // pass 2: stage ordered by bucket (re-read edges, L2-hot)
    for (int k = 0; k < BINCH / 1024; ++k) {
        int i0 = blockStart + k * 1024 + tid * 4;
        if (i0 + 3 < e) {
            int4 s4 = *(const int4*)(src + i0);
            int4 d4 = *(const int4*)(dst + i0);
            int bs[4] = { d4.x >> VSH, d4.y >> VSH, d4.z >> VSH, d4.w >> VSH };
            int pk[4] = { ((d4.x & (VPB - 1)) << 17) | s4.x,
                          ((d4.y & (VPB - 1)) << 17) | s4.y,
                          ((d4.z & (VPB - 1)) << 17) | s4.z,
                          ((d4.w & (VPB - 1)) << 17) | s4.w };
#pragma unroll
            for (int q = 0; q < 4; ++q) {
                int slot = atomicAdd(&lcur[bs[q]], 1);
                stage[slot] = pk[q];
                binid[slot] = (unsigned char)bs[q];
            }
        } else {
            for (int i = i0; i < e && i < i0 + 4; ++i) {
                int d = dst[i], b = d >> VSH;
                int slot = atomicAdd(&lcur[b], 1);
                stage[slot] = ((d & (VPB - 1)) << 17) | src[i];
                binid[slot] = (unsigned char)b;
            }
        }
    }
    __syncthreads();

    // pass 3: coalesced write-out per bucket run
    for (int j = tid; j < chunk; j += blockDim.x) {
        int b = binid[j];
        int idx = gbase[b] + (j - offs[b]);
        if (idx < CAP) binned[b * CAP + idx] = stage[j];
    }
}

// One block per bucket: LDS histogram (-> deg/cnt/dinv), PADDED LDS scan
// (segments rounded up to multiples of 8, filler = sentinel node n), one atomic
// for the bucket CSR base, LDS scatter, coalesced col write-out.
// Also emits xw[nid] = x[nid]*dinv[nid].
__global__ void k_bucket(const int* __restrict__ binned, const int* __restrict__ bktCur,
                         int* __restrict__ gtotal, int* __restrict__ rowstart,
                         int* __restrict__ cntG, float* __restrict__ dinv,
                         int* __restrict__ col, const float* __restrict__ x,
                         float* __restrict__ xw, int n) {
    __shared__ int buf[VPB];
    __shared__ int cur[VPB];
    __shared__ int colStage[CAP];
    __shared__ int sBase;
    const int tid = threadIdx.x;                 // blockDim = VPB
    const int b = blockIdx.x;
    const int nodeBase = b << VSH;
    const int count = min(bktCur[b], CAP);
    const int* bb = binned + b * CAP;

    buf[tid] = 0;
    __syncthreads();
    for (int i = tid; i < count; i += VPB)
        atomicAdd(&buf[bb[i] >> 17], 1);
    __syncthreads();
    int v = buf[tid];                            // real degree
    int vpad = (v + 7) & ~7;                     // padded segment length
    buf[tid] = vpad;
    __syncthreads();
    for (int off = 1; off < VPB; off <<= 1) {
        int t = (tid >= off) ? buf[tid - off] : 0;
        __syncthreads();
        buf[tid] += t;
        __syncthreads();
    }
    int excl = buf[tid] - vpad;
    if (tid == 0) sBase = atomicAdd(gtotal, buf[VPB - 1]);
    __syncthreads();
    int totalPad = buf[VPB - 1];
    int base = sBase;
    int nid = nodeBase + tid;
    if (nid < n) {
        float dv = rsqrtf((float)v + 1.0f);
        rowstart[nid] = base + excl;
        cntG[nid] = v;
        dinv[nid] = dv;
        const float* xr = x + (size_t)nid * 3;
        float* xo = xw + (size_t)nid * 3;
        xo[0] = xr[0] * dv;
        xo[1] = xr[1] * dv;
        xo[2] = xr[2] * dv;
    }
    cur[tid] = excl;
    for (int j = tid; j < totalPad && j < CAP; j += VPB) colStage[j] = n;
    __syncthreads();
    for (int i = tid; i < count; i += VPB) {
        int p = bb[i];
        int slot = atomicAdd(&cur[p >> 17], 1);
        colStage[slot] = p & 0x1FFFF;
    }
    __syncthreads();
    for (int j = tid; j < totalPad && j < CAP; j += VPB)
        col[base + j] = colStage[j];
}

// ---------------- layers ----------------

// Layer-0: aggregation commutes with the GEMM; payload xw = x*dinv pre-weighted.
__global__ void k_agg3(const float* __restrict__ xw, const float* __restrict__ dinv,
                       const int* __restrict__ rowstart, const int* __restrict__ cnt,
                       const int* __restrict__ col, float* __restrict__ xa, int n) {
    const int gl  = threadIdx.x & 3;
    const int grp = threadIdx.x >> 2;
    const int gpb = blockDim.x >> 2;
    for (int node = blockIdx.x * gpb + grp; node < n; node += gpb * gridDim.x) {
        float dn = dinv[node];
        float a = (gl < 3) ? xw[(size_t)node * 3 + gl] : 0.f;
        int s0 = rowstart[node];
        int cpad = (cnt[node] + 7) & ~7;
        for (int base = 0; base < cpad; base += 4) {
            int myidx = col[s0 + base + gl];
#pragma unroll
            for (int j = 0; j < 4; ++j) {
                int s = __shfl(myidx, j, 4);
                if (gl < 3) a += xw[(size_t)s * 3 + gl];   // sentinel row is zeros
            }
        }
        if (gl < 3) xa[(size_t)node * 3 + gl] = a * dn;
    }
}

// Fused layer-1 GEMM: t1s = ( relu(xa@W0 + b0) @ W1 ) * dinv, bf16 out.
__global__ __launch_bounds__(128) void k_l1(const float* __restrict__ xa,
        const float* __restrict__ W0, const float* __restrict__ b0,
        const float* __restrict__ W1, const float* __restrict__ dinv,
        unsigned short* __restrict__ t, int n) {
    __shared__ float hT[64 * GSTR];      // [k][node], stride GSTR
    __shared__ float Ws[64 * 64];        // [k][j] = W1
    __shared__ float W0s[3 * 64];
    __shared__ float b0s[64];
    __shared__ float xas[GN * 3];
    const int tid = threadIdx.x;
    const int n0 = blockIdx.x * GN;

    {
        const float4* W4 = (const float4*)W1;
        float4* Ws4 = (float4*)Ws;
        for (int i = tid; i < 1024; i += 128) Ws4[i] = W4[i];
    }
    if (tid < 64) b0s[tid] = b0[tid];
    for (int i = tid; i < 192; i += 128) W0s[i] = W0[i];
    for (int i = tid; i < GN * 3; i += 128) {
        int gi = n0 * 3 + i;
        xas[i] = (gi < n * 3) ? xa[gi] : 0.f;
    }
    __syncthreads();

    for (int p = 0; p < 16; ++p) {
        int idx = p * 128 + tid;
        int r = idx >> 4;
        int c4 = idx & 15;
        float x0 = xas[r * 3 + 0], x1 = xas[r * 3 + 1], x2 = xas[r * 3 + 2];
#pragma unroll
        for (int q = 0; q < 4; ++q) {
            int c = c4 * 4 + q;
            float h = fmaf(x0, W0s[c], fmaf(x1, W0s[64 + c], fmaf(x2, W0s[128 + c], b0s[c])));
            hT[c * GSTR + r] = fmaxf(h, 0.f);
        }
    }
    __syncthreads();

    const int lane = tid & 63;
    const int wave = tid >> 6;
    const int ng = lane >> 3;
    const int cg = lane & 7;
    const int nodeLoc = wave * 64 + ng * 8;

    float4 acc[8][2];
#pragma unroll
    for (int i = 0; i < 8; ++i) {
        acc[i][0] = make_float4(0.f, 0.f, 0.f, 0.f);
        acc[i][1] = make_float4(0.f, 0.f, 0.f, 0.f);
    }

#pragma unroll 4
    for (int k = 0; k < 64; ++k) {
        const float4* ap = (const float4*)(hT + k * GSTR + nodeLoc);
        const float4* bp = (const float4*)(Ws + k * 64 + cg * 8);
        float4 a0 = ap[0], a1 = ap[1];
        float4 b0v = bp[0], b1v = bp[1];
        const float av[8] = { a0.x, a0.y, a0.z, a0.w, a1.x, a1.y, a1.z, a1.w };
#pragma unroll
        for (int i = 0; i < 8; ++i) {
            acc[i][0].x = fmaf(av[i], b0v.x, acc[i][0].x);
            acc[i][0].y = fmaf(av[i], b0v.y, acc[i][0].y);
            acc[i][0].z = fmaf(av[i], b0v.z, acc[i][0].z);
            acc[i][0].w = fmaf(av[i], b0v.w, acc[i][0].w);
            acc[i][1].x = fmaf(av[i], b1v.x, acc[i][1].x);
            acc[i][1].y = fmaf(av[i], b1v.y, acc[i][1].y);
            acc[i][1].z = fmaf(av[i], b1v.z, acc[i][1].z);
            acc[i][1].w = fmaf(av[i], b1v.w, acc[i][1].w);
        }
    }

#pragma unroll
    for (int i = 0; i < 8; ++i) {
        int row = n0 + nodeLoc + i;
        if (row < n) {
            float dv = dinv[row];
            uint4 pk;
            pk.x = packbf2(acc[i][0].x * dv, acc[i][0].y * dv);
            pk.y = packbf2(acc[i][0].z * dv, acc[i][0].w * dv);
            pk.z = packbf2(acc[i][1].x * dv, acc[i][1].y * dv);
            pk.w = packbf2(acc[i][1].z * dv, acc[i][1].w * dv);
            *(uint4*)(t + (size_t)row * 64 + cg * 8) = pk;
        }
    }
}

// FUSED layer-1 aggregation + layer-2 GEMM (GN2=64 nodes/block, bf16 LDS tile):
//   h2[r][j] = relu(b1[j] + dn*(t1s[r][j] + sum_s t1s[s][j]))   (phase A -> hP bf16x2)
//   t2s = (h2 @ W2) * dinv, bf16 out                            (phase B)
// LDS ~25KB -> 6 blocks/CU; grid 1563 -> gather phase keeps high occupancy.
__global__ __launch_bounds__(256) void k_aggemm(const unsigned short* __restrict__ t,
        const float* __restrict__ dinv, const int* __restrict__ rowstart,
        const int* __restrict__ cnt, const int* __restrict__ col,
        const float* __restrict__ b, const float* __restrict__ W,
        unsigned short* __restrict__ out, int n) {
    __shared__ unsigned hP[32 * PSTR];   // [channel pair][node], packed bf16x2
    __shared__ float Ws[64 * 64];        // [k][j] = W2
    const int tid = threadIdx.x;
    const int n0 = blockIdx.x * GN2;

    // stage W2
    {
        const float4* W4 = (const float4*)W;
        float4* Ws4 = (float4*)Ws;
        for (int i = tid; i < 1024; i += 256) Ws4[i] = W4[i];
    }

    // phase A: 32 groups x 8 lanes; 2 nodes per group; gather + relu + pack
    {
        const int gl  = tid & 7;          // lane in group (8 bf16 channels)
        const int grp = tid >> 3;         // 0..31
        const float4 bv0 = ((const float4*)b)[gl * 2];
        const float4 bv1 = ((const float4*)b)[gl * 2 + 1];
#pragma unroll
        for (int i = 0; i < 2; ++i) {
            int r = grp * 2 + i;          // local node 0..63
            int node = n0 + r;
            float h0 = 0.f, h1 = 0.f, h2 = 0.f, h3 = 0.f;
            float h4 = 0.f, h5 = 0.f, h6 = 0.f, h7 = 0.f;
            if (node < n) {
                float dn = dinv[node];
                uint4 tv = *(const uint4*)(t + (size_t)node * 64 + gl * 8);
                float a0 = bflo(tv.x), a1 = bfhi(tv.x), a2 = bflo(tv.y), a3 = bfhi(tv.y);
                float a4 = bflo(tv.z), a5 = bfhi(tv.z), a6 = bflo(tv.w), a7 = bfhi(tv.w);
                int s0 = rowstart[node];
                int cpad = (cnt[node] + 7) & ~7;
                for (int base = 0; base < cpad; base += 8) {
                    int myidx = col[s0 + base + gl];
#pragma unroll
                    for (int j = 0; j < 8; ++j) {
                        int s = __shfl(myidx, j, 8);
                        uint4 g = *(const uint4*)(t + (size_t)s * 64 + gl * 8);
                        a0 += bflo(g.x); a1 += bfhi(g.x);
                        a2 += bflo(g.y); a3 += bfhi(g.y);
                        a4 += bflo(g.z); a5 += bfhi(g.z);
                        a6 += bflo(g.w); a7 += bfhi(g.w);
                    }
                }
                h0 = fmaxf(fmaf(a0, dn, bv0.x), 0.f);
                h1 = fmaxf(fmaf(a1, dn, bv0.y), 0.f);
                h2 = fmaxf(fmaf(a2, dn, bv0.z), 0.f);
                h3 = fmaxf(fmaf(a3, dn, bv0.w), 0.f);
                h4 = fmaxf(fmaf(a4, dn, bv1.x), 0.f);
                h5 = fmaxf(fmaf(a5, dn, bv1.y), 0.f);
                h6 = fmaxf(fmaf(a6, dn, bv1.z), 0.f);
                h7 = fmaxf(fmaf(a7, dn, bv1.w), 0.f);
            }
            int c2 = gl * 4;              // pair-row base (channels 2c2, 2c2+1)
            hP[(c2 + 0) * PSTR + r] = packbf2(h0, h1);
            hP[(c2 + 1) * PSTR + r] = packbf2(h2, h3);
            hP[(c2 + 2) * PSTR + r] = packbf2(h4, h5);
            hP[(c2 + 3) * PSTR + r] = packbf2(h6, h7);
        }
    }
    __syncthreads();

    // phase B: 4 waves; thread tile = 4 nodes x 4 cols; 32 pair-iterations.
    const int lane = tid & 63;
    const int wave = tid >> 6;           // 0..3
    const int ng = lane >> 4;            // 0..3
    const int cg = lane & 15;            // 0..15
    const int nodeLoc = wave * 16 + ng * 4;

    float4 acc[4];
#pragma unroll
    for (int i = 0; i < 4; ++i) acc[i] = make_float4(0.f, 0.f, 0.f, 0.f);

#pragma unroll 4
    for (int kk = 0; kk < 32; ++kk) {
        uint4 ap = *(const uint4*)(hP + kk * PSTR + nodeLoc);   // 4 nodes' pairs
        float4 blo = *(const float4*)(Ws + (2 * kk) * 64 + cg * 4);
        float4 bhi = *(const float4*)(Ws + (2 * kk + 1) * 64 + cg * 4);
        const float alo[4] = { bflo(ap.x), bflo(ap.y), bflo(ap.z), bflo(ap.w) };
        const float ahi[4] = { bfhi(ap.x), bfhi(ap.y), bfhi(ap.z), bfhi(ap.w) };
#pragma unroll
        for (int i = 0; i < 4; ++i) {
            acc[i].x = fmaf(alo[i], blo.x, acc[i].x);
            acc[i].y = fmaf(alo[i], blo.y, acc[i].y);
            acc[i].z = fmaf(alo[i], blo.z, acc[i].z);
            acc[i].w = fmaf(alo[i], blo.w, acc[i].w);
            acc[i].x = fmaf(ahi[i], bhi.x, acc[i].x);
            acc[i].y = fmaf(ahi[i], bhi.y, acc[i].y);
            acc[i].z = fmaf(ahi[i], bhi.z, acc[i].z);
            acc[i].w = fmaf(ahi[i], bhi.w, acc[i].w);
        }
    }

#pragma unroll
    for (int i = 0; i < 4; ++i) {
        int row = n0 + nodeLoc + i;
        if (row < n) {
            float dv = dinv[row];
            uint2 pk;
            pk.x = packbf2(acc[i].x * dv, acc[i].y * dv);
            pk.y = packbf2(acc[i].z * dv, acc[i].w * dv);
            *(uint2*)(out + (size_t)row * 64 + cg * 4) = pk;
        }
    }
}

// Final layer fused with output head:
// h3[j] = relu( b2[j] + dn*(ts[n][j] + sum ts[s][j]) ); out[n] = sigmoid(h3·Wo + bo)
__global__ void k_agg_out(const unsigned short* __restrict__ t, const float* __restrict__ dinv,
                          const int* __restrict__ rowstart, const int* __restrict__ cnt,
                          const int* __restrict__ col,
                          const float* __restrict__ b, const float* __restrict__ Wo,
                          const float* __restrict__ bo, float* __restrict__ out, int n) {
    const int gl  = threadIdx.x & 7;
    const int grp = threadIdx.x >> 3;
    const int gpb = blockDim.x >> 3;
    const float4 bv0 = ((const float4*)b)[gl * 2];
    const float4 bv1 = ((const float4*)b)[gl * 2 + 1];
    const float4 wv0 = ((const float4*)Wo)[gl * 2];
    const float4 wv1 = ((const float4*)Wo)[gl * 2 + 1];
    const float bo0 = bo[0];
    for (int node = blockIdx.x * gpb + grp; node < n; node += gpb * gridDim.x) {
        float dn = dinv[node];
        uint4 tv = *(const uint4*)(t + (size_t)node * 64 + gl * 8);
        float a0 = bflo(tv.x), a1 = bfhi(tv.x), a2 = bflo(tv.y), a3 = bfhi(tv.y);
        float a4 = bflo(tv.z), a5 = bfhi(tv.z), a6 = bflo(tv.w), a7 = bfhi(tv.w);
        int s0 = rowstart[node];
        int cpad = (cnt[node] + 7) & ~7;
        for (int base = 0; base < cpad; base += 8) {
            int myidx = col[s0 + base + gl];
#pragma unroll
            for (int j = 0; j < 8; ++j) {
                int s = __shfl(myidx, j, 8);
                uint4 g = *(const uint4*)(t + (size_t)s * 64 + gl * 8);
                a0 += bflo(g.x); a1 += bfhi(g.x);
                a2 += bflo(g.y); a3 += bfhi(g.y);
                a4 += bflo(g.z); a5 += bfhi(g.z);
                a6 += bflo(g.w); a7 += bfhi(g.w);
            }
        }
        float v = fmaxf(fmaf(a0, dn, bv0.x), 0.f) * wv0.x
                + fmaxf(fmaf(a1, dn, bv0.y), 0.f) * wv0.y
                + fmaxf(fmaf(a2, dn, bv0.z), 0.f) * wv0.z
                + fmaxf(fmaf(a3, dn, bv0.w), 0.f) * wv0.w
                + fmaxf(fmaf(a4, dn, bv1.x), 0.f) * wv1.x
                + fmaxf(fmaf(a5, dn, bv1.y), 0.f) * wv1.y
                + fmaxf(fmaf(a6, dn, bv1.z), 0.f) * wv1.z
                + fmaxf(fmaf(a7, dn, bv1.w), 0.f) * wv1.w;
#pragma unroll
        for (int off = 4; off > 0; off >>= 1) v += __shfl_xor(v, off, 8);
        if (gl == 0) out[node] = 1.0f / (1.0f + expf(-(v + bo0)));
    }
}

// ---------------- launch ----------------

extern "C" void kernel_launch(void* const* d_in, const int* in_sizes, int n_in,
                              void* d_out, int out_size, void* d_ws, size_t ws_size,
                              hipStream_t stream) {
    const float* x  = (const float*)d_in[0];
    const int*   ei = (const int*)d_in[1];
    const float* W0 = (const float*)d_in[2];
    const float* b0 = (const float*)d_in[3];
    const float* W1 = (const float*)d_in[4];
    const float* b1 = (const float*)d_in[5];
    const float* W2 = (const float*)d_in[6];
    const float* b2 = (const float*)d_in[7];
    const float* Wo = (const float*)d_in[8];
    const float* bo = (const float*)d_in[9];
    float* out = (float*)d_out;

    const int N = in_sizes[0] / 3;
    const int E = in_sizes[1] / 2;
    const int* src = ei;
    const int* dst = ei + E;
    const int nb = (N + VPB - 1) >> VSH;

    char* w = (char*)d_ws;
    size_t off = 0;
    auto take = [&](size_t bytes) -> void* {
        void* p = w + off;
        off = (off + bytes + 255) & ~(size_t)255;
        return p;
    };
    float* dinv     = (float*)take((size_t)N * 4);
    int*   cnt      = (int*)take((size_t)N * 4);
    int*   rowstart = (int*)take((size_t)N * 4);
    int*   gtotal   = (int*)take(4);
    int*   bktCur   = (int*)take(MAXB * 4);
    float* xw       = (float*)take((size_t)(N + 1) * 3 * 4);      // +sentinel row
    float* xa       = (float*)take((size_t)N * 3 * 4);
    int*   col      = (int*)take(((size_t)E + 8 * (size_t)N) * 4); // padded CSR
    unsigned short* A  = (unsigned short*)take((size_t)(N + 1) * 64 * 2); // bf16 t1s (+sentinel)
    unsigned short* A2 = (unsigned short*)take((size_t)(N + 1) * 64 * 2); // bf16 t2s (+sentinel)
    int*   binned   = (int*)take((size_t)MAXB * CAP * 4);
    (void)ws_size; (void)n_in; (void)out_size;

    const int TB = 256;
    // graph prep: bin -> per-bucket padded CSR build (also emits dinv + xw)
    k_zero  <<<1, 256, 0, stream>>>(bktCur, gtotal, A + (size_t)N * 64,
                                    A2 + (size_t)N * 64, xw + (size_t)N * 3);
    k_bin   <<<(E + BINCH - 1) / BINCH, TB, 0, stream>>>(src, dst, bktCur, binned, E, nb);
    k_bucket<<<nb, VPB, 0, stream>>>(binned, bktCur, gtotal, rowstart, cnt, dinv, col, x, xw, N);

    // layer 0 agg (3-dim, pre-weighted payload, 4-lane groups)
    k_agg3  <<<2048, TB, 0, stream>>>(xw, dinv, rowstart, cnt, col, xa, N);
    // layer 1: fused h0-compute + GEMM W1 + dinv-scale -> bf16 A
    k_l1    <<<(N + GN - 1) / GN, 128, 0, stream>>>(xa, W0, b0, W1, dinv, A, N);
    // FUSED: layer-1 aggregation + layer-2 GEMM -> bf16 A2 (h2 never materialized)
    k_aggemm<<<(N + GN2 - 1) / GN2, 256, 0, stream>>>(A, dinv, rowstart, cnt, col,
                                                      b1, W2, A2, N);
    // layer-2 aggregation + output head
    k_agg_out<<<2048, TB, 0, stream>>>(A2, dinv, rowstart, cnt, col, b2, Wo, bo, out, N);
}